// Round 1
// baseline (23097.694 us; speedup 1.0000x reference)
//
#include <hip/hip_runtime.h>
#include <math.h>

#define LAY 20
#define HID 512
#define NH 8
#define DH 64
#define OUTC 1000
#define SEQ 197
#define BATCH 64
#define TT (BATCH*SEQ)      /* 12608 tokens */
#define NPTOK (BATCH*196)   /* 12544 patch tokens */
#define IN_DIM 768

__device__ __forceinline__ float posemb(int i, int j){
  float je = (float)(j & ~1);
  float ang = (float)i * powf(10000.0f, -je * (1.0f/(float)HID));
  return (j & 1) ? cosf(ang) : sinf(ang);
}

__device__ __forceinline__ float gelu_exact(float x){
  return 0.5f * x * (1.0f + erff(x * 0.70710678118654752f));
}

// ---------------- patchify: x[64,3,224,224] -> p[12544,768] ----------------
__global__ __launch_bounds__(256)
void patchify_kernel(const float* __restrict__ x, float* __restrict__ p){
  int idx = blockIdx.x * 256 + threadIdx.x;     // total 12544*768 = 37632*256
  int r   = idx / 768, cdx = idx - r * 768;
  int n   = r / 196,  pp  = r - n * 196;
  int pr  = pp / 14,  pc  = pp - pr * 14;
  int c   = cdx >> 8, rem = cdx & 255;
  int ph  = rem >> 4, pw  = rem & 15;
  p[idx] = x[ (((size_t)(n*3 + c)*224) + pr*16 + ph)*224 + pc*16 + pw ];
}

// ---------------- cls row: h[n,0,:] = cls + pos[0] ----------------
__global__ __launch_bounds__(512)
void cls_kernel(const float* __restrict__ cls, float* __restrict__ h){
  int n = blockIdx.x, e = threadIdx.x;
  h[(size_t)n*SEQ*HID + e] = cls[e] + posemb(0, e);
}

// ---------------- generic tiled GEMM, C = A[M,K] @ B[K,N] (+epilogue) -----
// EPI: 1 = bias+GELU store, 2 = bias + add into C (residual), 3 = embed
// requires M%64==0, N%64==0, K%16==0
template<int EPI>
__global__ __launch_bounds__(256)
void gemm_kernel(const float* __restrict__ A, const float* __restrict__ B,
                 const float* __restrict__ bias, float* __restrict__ C,
                 int M, int N, int K){
  __shared__ float As[64][17];
  __shared__ float Bs[16][64];
  int t  = threadIdx.x;
  int tx = t & 15, ty = t >> 4;
  int rb = blockIdx.y * 64, cb = blockIdx.x * 64;
  float acc[4][4] = {};
  int arow = t >> 2,  akk  = (t & 3) << 2;
  int bkr  = t >> 4,  bcol = (t & 15) << 2;

  for (int k0 = 0; k0 < K; k0 += 16){
    float4 av = *(const float4*)&A[(size_t)(rb + arow)*K + k0 + akk];
    float4 bv = *(const float4*)&B[(size_t)(k0 + bkr)*N + cb + bcol];
    As[arow][akk+0] = av.x; As[arow][akk+1] = av.y;
    As[arow][akk+2] = av.z; As[arow][akk+3] = av.w;
    *(float4*)&Bs[bkr][bcol] = bv;
    __syncthreads();
    #pragma unroll
    for (int kk = 0; kk < 16; ++kk){
      float b0 = Bs[kk][tx*4+0], b1 = Bs[kk][tx*4+1];
      float b2 = Bs[kk][tx*4+2], b3 = Bs[kk][tx*4+3];
      #pragma unroll
      for (int m = 0; m < 4; ++m){
        float a = As[ty*4+m][kk];
        acc[m][0] += a*b0; acc[m][1] += a*b1;
        acc[m][2] += a*b2; acc[m][3] += a*b3;
      }
    }
    __syncthreads();
  }

  #pragma unroll
  for (int m = 0; m < 4; ++m){
    int row = rb + ty*4 + m;
    #pragma unroll
    for (int n = 0; n < 4; ++n){
      int col = cb + tx*4 + n;
      float val = acc[m][n] + bias[col];
      if (EPI == 1){
        C[(size_t)row*N + col] = gelu_exact(val);
      } else if (EPI == 2){
        C[(size_t)row*N + col] += val;
      } else { // EPI == 3: embed scatter, row is patch-token index
        int bn = row / 196, sp = row - bn*196;
        size_t dst = ((size_t)bn*SEQ + 1 + sp)*HID + col;
        C[dst] = val + posemb(1 + sp, col);
      }
    }
  }
}

// ---------------- LayerNorm over last dim (512) ----------------
__global__ __launch_bounds__(256)
void ln_kernel(const float* __restrict__ x, const float* __restrict__ g,
               const float* __restrict__ b, float* __restrict__ y){
  int tok = blockIdx.x, t = threadIdx.x;
  const float* xp = x + (size_t)tok*HID;
  float v1 = xp[t], v2 = xp[t + 256];
  __shared__ float red[4];
  float s = v1 + v2;
  #pragma unroll
  for (int off = 32; off; off >>= 1) s += __shfl_xor(s, off);
  if ((t & 63) == 0) red[t >> 6] = s;
  __syncthreads();
  float mean = (red[0] + red[1] + red[2] + red[3]) * (1.0f/512.0f);
  __syncthreads();
  float d1 = v1 - mean, d2 = v2 - mean;
  s = d1*d1 + d2*d2;
  #pragma unroll
  for (int off = 32; off; off >>= 1) s += __shfl_xor(s, off);
  if ((t & 63) == 0) red[t >> 6] = s;
  __syncthreads();
  float var = (red[0] + red[1] + red[2] + red[3]) * (1.0f/512.0f);
  float rs  = rsqrtf(var + 1e-5f);
  float* yp = y + (size_t)tok*HID;
  yp[t]       = d1*rs*g[t]       + b[t];
  yp[t + 256] = d2*rs*g[t + 256] + b[t + 256];
}

// ---------------- fused per-head QKV projection ----------------
// q[n,s,h*64+e] = sum_d y[n,s,h*64+d] * W[h,e,d] + b[h,e]
// grid.x: token groups of 8, grid.y: 0=q 1=k 2=v, block 512
__global__ __launch_bounds__(512)
void qkv_kernel(const float* __restrict__ y,
                const float* __restrict__ Wq, const float* __restrict__ Wk,
                const float* __restrict__ Wv,
                const float* __restrict__ bq, const float* __restrict__ bk,
                const float* __restrict__ bv,
                float* __restrict__ q, float* __restrict__ k,
                float* __restrict__ v){
  const float* W; const float* bias; float* out;
  if (blockIdx.y == 0)      { W = Wq; bias = bq; out = q; }
  else if (blockIdx.y == 1) { W = Wk; bias = bk; out = k; }
  else                      { W = Wv; bias = bv; out = v; }
  int tok0 = blockIdx.x * 8;
  int t = threadIdx.x;
  __shared__ float yl[8*512];
  for (int i = t; i < 8*512; i += 512) yl[i] = y[(size_t)tok0*HID + i];
  __syncthreads();
  int hh = t >> 6;
  const float4* wr = (const float4*)&W[(size_t)t * 64];  // row t = h*64+e
  float4 w4[16];
  #pragma unroll
  for (int j = 0; j < 16; ++j) w4[j] = wr[j];
  float bs = bias[t];
  for (int tk = 0; tk < 8; ++tk){
    const float4* yr = (const float4*)&yl[tk*512 + hh*64];
    float acc = 0.f;
    #pragma unroll
    for (int j = 0; j < 16; ++j){
      float4 yv = yr[j];
      acc += yv.x*w4[j].x + yv.y*w4[j].y + yv.z*w4[j].z + yv.w*w4[j].w;
    }
    out[(size_t)(tok0 + tk)*HID + t] = acc + bs;
  }
}

// ---------------- flash attention + residual add into h ----------------
// grid: BATCH*NH blocks, block 256; lane r = q row; K/V tiles of 32 in LDS
#define ABLK 32
__global__ __launch_bounds__(256)
void attn_kernel(const float* __restrict__ q, const float* __restrict__ k,
                 const float* __restrict__ v, float* __restrict__ h){
  int nh = blockIdx.x;
  int n  = nh >> 3, hd = nh & 7;
  __shared__ float kl[ABLK*64];
  __shared__ float vl[ABLK*64];
  int t = threadIdx.x;
  int r = t;
  bool active = r < SEQ;
  size_t base = ((size_t)n*SEQ + (active ? r : 0))*HID + hd*64;
  float qreg[64], acc[64];
  if (active){
    #pragma unroll
    for (int d = 0; d < 64; d += 4){
      float4 qv = *(const float4*)&q[base + d];
      qreg[d+0] = qv.x * 0.125f; qreg[d+1] = qv.y * 0.125f;
      qreg[d+2] = qv.z * 0.125f; qreg[d+3] = qv.w * 0.125f;
    }
  }
  #pragma unroll
  for (int d = 0; d < 64; ++d) acc[d] = 0.f;
  float m = -1e30f, l = 0.f;

  for (int j0 = 0; j0 < SEQ; j0 += ABLK){
    int cnt = min(ABLK, SEQ - j0);
    __syncthreads();
    for (int i = t; i < ABLK*64; i += 256){
      int jj = i >> 6, d = i & 63;
      float kv = 0.f, vv = 0.f;
      if (jj < cnt){
        size_t src = ((size_t)n*SEQ + j0 + jj)*HID + hd*64 + d;
        kv = k[src]; vv = v[src];
      }
      kl[i] = kv; vl[i] = vv;
    }
    __syncthreads();
    if (active){
      for (int jj = 0; jj < cnt; ++jj){
        float s0 = 0.f, s1 = 0.f, s2 = 0.f, s3 = 0.f;
        #pragma unroll
        for (int d = 0; d < 64; d += 4){
          s0 += qreg[d+0]*kl[jj*64+d+0];
          s1 += qreg[d+1]*kl[jj*64+d+1];
          s2 += qreg[d+2]*kl[jj*64+d+2];
          s3 += qreg[d+3]*kl[jj*64+d+3];
        }
        float s  = (s0 + s1) + (s2 + s3);
        float mn = fmaxf(m, s);
        float corr = __expf(m - mn);
        float p    = __expf(s - mn);
        l = l*corr + p;
        m = mn;
        #pragma unroll
        for (int d = 0; d < 64; ++d)
          acc[d] = acc[d]*corr + p*vl[jj*64+d];
      }
    }
  }
  if (active){
    float inv = 1.0f / l;
    #pragma unroll
    for (int d = 0; d < 64; ++d)
      h[base + d] += acc[d] * inv;
  }
}

// ---------------- head: logits = h[:,0] @ W + b, softmax ----------------
__global__ __launch_bounds__(256)
void head_kernel(const float* __restrict__ h, const float* __restrict__ W,
                 const float* __restrict__ b, float* __restrict__ out){
  int n = blockIdx.x, t = threadIdx.x;
  __shared__ float hl[512];
  __shared__ float logits[OUTC];
  __shared__ float red[4];
  hl[t]       = h[(size_t)n*SEQ*HID + t];
  hl[t + 256] = h[(size_t)n*SEQ*HID + t + 256];
  __syncthreads();
  for (int j = 0; j < 4; ++j){
    int e = t + j*256;
    if (e < OUTC){
      float a0 = b[e];
      #pragma unroll 4
      for (int kx = 0; kx < 512; ++kx) a0 += hl[kx] * W[(size_t)kx*OUTC + e];
      logits[e] = a0;
    }
  }
  __syncthreads();
  float mx = -1e30f;
  for (int j = 0; j < 4; ++j){ int e = t + j*256; if (e < OUTC) mx = fmaxf(mx, logits[e]); }
  #pragma unroll
  for (int off = 32; off; off >>= 1) mx = fmaxf(mx, __shfl_xor(mx, off));
  if ((t & 63) == 0) red[t >> 6] = mx;
  __syncthreads();
  mx = fmaxf(fmaxf(red[0], red[1]), fmaxf(red[2], red[3]));
  __syncthreads();
  float sum = 0.f;
  for (int j = 0; j < 4; ++j){ int e = t + j*256; if (e < OUTC) sum += expf(logits[e] - mx); }
  #pragma unroll
  for (int off = 32; off; off >>= 1) sum += __shfl_xor(sum, off);
  if ((t & 63) == 0) red[t >> 6] = sum;
  __syncthreads();
  sum = red[0] + red[1] + red[2] + red[3];
  float inv = 1.0f / sum;
  for (int j = 0; j < 4; ++j){
    int e = t + j*256;
    if (e < OUTC) out[(size_t)n*OUTC + e] = expf(logits[e] - mx) * inv;
  }
}

extern "C" void kernel_launch(void* const* d_in, const int* in_sizes, int n_in,
                              void* d_out, int out_size, void* d_ws, size_t ws_size,
                              hipStream_t stream){
  const float* x       = (const float*)d_in[0];
  const float* embed_W = (const float*)d_in[1];
  const float* embed_b = (const float*)d_in[2];
  const float* cls     = (const float*)d_in[3];
  const float* ln1_g   = (const float*)d_in[4];
  const float* ln1_b   = (const float*)d_in[5];
  const float* qW      = (const float*)d_in[6];
  const float* qb      = (const float*)d_in[7];
  const float* kW      = (const float*)d_in[8];
  const float* kb      = (const float*)d_in[9];
  const float* vW      = (const float*)d_in[10];
  const float* vb      = (const float*)d_in[11];
  const float* ln2_g   = (const float*)d_in[12];
  const float* ln2_b   = (const float*)d_in[13];
  const float* mlp1_W  = (const float*)d_in[14];
  const float* mlp1_b  = (const float*)d_in[15];
  const float* mlp2_W  = (const float*)d_in[16];
  const float* mlp2_b  = (const float*)d_in[17];
  const float* head_W  = (const float*)d_in[18];
  const float* head_b  = (const float*)d_in[19];
  float* out = (float*)d_out;

  float* ws = (float*)d_ws;
  float* h  = ws;
  float* y  = h + (size_t)TT*HID;
  float* q  = y + (size_t)TT*HID;
  float* k  = q + (size_t)TT*HID;
  float* v  = k + (size_t)TT*HID;
  float* z1 = v + (size_t)TT*HID;   // TT*2048
  float* p  = z1;                   // patch matrix overlaps z1 (only used pre-loop)

  patchify_kernel<<<(NPTOK*IN_DIM)/256, 256, 0, stream>>>(x, p);
  cls_kernel<<<BATCH, 512, 0, stream>>>(cls, h);
  gemm_kernel<3><<<dim3(HID/64, NPTOK/64), 256, 0, stream>>>(
      p, embed_W, embed_b, h, NPTOK, HID, IN_DIM);

  for (int l = 0; l < LAY; ++l){
    ln_kernel<<<TT, 256, 0, stream>>>(h, ln1_g + l*HID, ln1_b + l*HID, y);
    qkv_kernel<<<dim3(TT/8, 3), 512, 0, stream>>>(
        y,
        qW + (size_t)l*NH*DH*DH, kW + (size_t)l*NH*DH*DH, vW + (size_t)l*NH*DH*DH,
        qb + (size_t)l*HID, kb + (size_t)l*HID, vb + (size_t)l*HID,
        q, k, v);
    attn_kernel<<<BATCH*NH, 256, 0, stream>>>(q, k, v, h);
    ln_kernel<<<TT, 256, 0, stream>>>(h, ln2_g + l*HID, ln2_b + l*HID, y);
    gemm_kernel<1><<<dim3((4*HID)/64, TT/64), 256, 0, stream>>>(
        y, mlp1_W + (size_t)l*HID*4*HID, mlp1_b + (size_t)l*4*HID, z1,
        TT, 4*HID, HID);
    gemm_kernel<2><<<dim3(HID/64, TT/64), 256, 0, stream>>>(
        z1, mlp2_W + (size_t)l*4*HID*HID, mlp2_b + (size_t)l*HID, h,
        TT, HID, 4*HID);
  }

  head_kernel<<<BATCH, 256, 0, stream>>>(h, head_W, head_b, out);
}

// Round 2
// 9999.981 us; speedup vs baseline: 2.3098x; 2.3098x over previous
//
#include <hip/hip_runtime.h>
#include <hip/hip_bf16.h>
#include <math.h>

#define LAY 20
#define HID 512
#define NH 8
#define DH 64
#define OUTC 1000
#define SEQ 197
#define BATCH 64
#define TT (BATCH*SEQ)      /* 12608 tokens */
#define MPAD 12672          /* 99*128 */
#define NPTOK (BATCH*196)   /* 12544 = 98*128 */
#define IN_DIM 768

typedef __attribute__((ext_vector_type(8))) short bf16x8;
typedef __attribute__((ext_vector_type(4))) float f32x4;

__device__ __forceinline__ ushort f2bf(float f){
  __hip_bfloat16 h = __float2bfloat16(f);
  return *(ushort*)&h;
}
__device__ __forceinline__ float bf2f(ushort u){
  __hip_bfloat16 h = *(__hip_bfloat16*)&u;
  return __bfloat162float(h);
}

__device__ __forceinline__ float posemb(int i, int j){
  float je = (float)(j & ~1);
  float ang = (float)i * powf(10000.0f, -je * (1.0f/(float)HID));
  return (j & 1) ? cosf(ang) : sinf(ang);
}

__device__ __forceinline__ float gelu_exact(float x){
  return 0.5f * x * (1.0f + erff(x * 0.70710678118654752f));
}

__device__ __forceinline__ void gld_lds16(const ushort* g, ushort* l){
  __builtin_amdgcn_global_load_lds((const __attribute__((address_space(1))) void*)g,
                                   (__attribute__((address_space(3))) void*)l, 16, 0, 0);
}

// ------- weight convert+transpose: src fp32 [R][C] -> dst bf16 [C][R] -------
__global__ __launch_bounds__(256)
void convt_kernel(const float* __restrict__ src, ushort* __restrict__ dst,
                  int R, int C){
  __shared__ float tile[32][33];
  const float* s = src + (size_t)blockIdx.z * R * C;
  ushort* d      = dst + (size_t)blockIdx.z * R * C;
  int r0 = blockIdx.y * 32, c0 = blockIdx.x * 32;
  int tc = threadIdx.x & 31, tr = threadIdx.x >> 5;
  #pragma unroll
  for (int i = 0; i < 4; ++i)
    tile[tr + i*8][tc] = s[(size_t)(r0 + tr + i*8)*C + c0 + tc];
  __syncthreads();
  #pragma unroll
  for (int i = 0; i < 4; ++i)
    d[(size_t)(c0 + tr + i*8)*R + r0 + tc] = f2bf(tile[tc][tr + i*8]);
}

// ---------------- patchify: x[64,3,224,224] -> p_bf16[12544,768] ----------------
__global__ __launch_bounds__(256)
void patchify_kernel(const float* __restrict__ x, ushort* __restrict__ p){
  int idx = blockIdx.x * 256 + threadIdx.x;
  int r   = idx / 768, cdx = idx - r * 768;
  int n   = r / 196,  pp  = r - n * 196;
  int pr  = pp / 14,  pc  = pp - pr * 14;
  int c   = cdx >> 8, rem = cdx & 255;
  int ph  = rem >> 4, pw  = rem & 15;
  p[idx] = f2bf(x[ (((size_t)(n*3 + c)*224) + pr*16 + ph)*224 + pc*16 + pw ]);
}

// ---------------- cls row ----------------
__global__ __launch_bounds__(512)
void cls_kernel(const float* __restrict__ cls, float* __restrict__ h){
  int n = blockIdx.x, e = threadIdx.x;
  h[(size_t)n*SEQ*HID + e] = cls[e] + posemb(0, e);
}

// ---------------- MFMA GEMM: C = A[M,K](bf16) @ Bt[N,K](bf16)^T ----------------
// 128x128 tile, BK=64, 4 waves (2x2), 16x16x32 bf16 MFMA, global_load_lds staging.
// EPI: 1 = bias+GELU -> bf16 store, 2 = bias + add into fp32 C (rows < Mreal),
//      3 = embed: bias + posemb, scatter to h
template<int EPI>
__global__ __launch_bounds__(256)
void gemm_mfma(const ushort* __restrict__ A, const ushort* __restrict__ Bt,
               const float* __restrict__ bias, void* __restrict__ Cv,
               int K, int N, int Mreal){
  __shared__ short As[128*64];
  __shared__ short Bs[128*64];
  int t = threadIdx.x;
  int lane = t & 63, wave = t >> 6;
  int wr = wave >> 1, wc = wave & 1;
  int l16 = lane & 15, lq = lane >> 4;
  int rb = blockIdx.y * 128, cb = blockIdx.x * 128;

  int srow = t >> 3;              // 0..31 within issue
  int skoff = (t & 7) * 8;        // k element offset
  const ushort* Ab = A  + (size_t)(rb + srow)*K + skoff;
  const ushort* Bb = Bt + (size_t)(cb + srow)*K + skoff;
  short* Asl = &As[t*8];
  short* Bsl = &Bs[t*8];

  f32x4 acc[4][4];
  #pragma unroll
  for (int m = 0; m < 4; ++m)
    #pragma unroll
    for (int n = 0; n < 4; ++n)
      acc[m][n] = (f32x4){0.f, 0.f, 0.f, 0.f};

  for (int k0 = 0; k0 < K; k0 += 64){
    #pragma unroll
    for (int i = 0; i < 4; ++i){
      gld_lds16((const ushort*)(Ab + (size_t)(i*32)*K + k0), (ushort*)(Asl + i*2048));
      gld_lds16((const ushort*)(Bb + (size_t)(i*32)*K + k0), (ushort*)(Bsl + i*2048));
    }
    __syncthreads();
    #pragma unroll
    for (int kc = 0; kc < 2; ++kc){
      bf16x8 af[4], bfr[4];
      #pragma unroll
      for (int m = 0; m < 4; ++m)
        af[m] = *(bf16x8*)&As[(wr*64 + m*16 + l16)*64 + kc*32 + lq*8];
      #pragma unroll
      for (int n = 0; n < 4; ++n)
        bfr[n] = *(bf16x8*)&Bs[(wc*64 + n*16 + l16)*64 + kc*32 + lq*8];
      #pragma unroll
      for (int m = 0; m < 4; ++m)
        #pragma unroll
        for (int n = 0; n < 4; ++n)
          acc[m][n] = __builtin_amdgcn_mfma_f32_16x16x32_bf16(af[m], bfr[n], acc[m][n], 0, 0, 0);
    }
    __syncthreads();
  }

  #pragma unroll
  for (int m = 0; m < 4; ++m){
    #pragma unroll
    for (int n = 0; n < 4; ++n){
      int col  = cb + wc*64 + n*16 + l16;
      int row0 = rb + wr*64 + m*16 + lq*4;
      float bv = bias[col];
      #pragma unroll
      for (int j = 0; j < 4; ++j){
        int row = row0 + j;
        float val = acc[m][n][j] + bv;
        if (EPI == 1){
          ((ushort*)Cv)[(size_t)row*N + col] = f2bf(gelu_exact(val));
        } else if (EPI == 2){
          if (row < Mreal) ((float*)Cv)[(size_t)row*N + col] += val;
        } else { // EPI == 3
          int bn = row / 196, sp = row - bn*196;
          ((float*)Cv)[((size_t)bn*SEQ + 1 + sp)*HID + col] = val + posemb(1 + sp, col);
        }
      }
    }
  }
}

// ---------------- LayerNorm (fp32 in, bf16 out) ----------------
__global__ __launch_bounds__(256)
void ln_kernel(const float* __restrict__ x, const float* __restrict__ g,
               const float* __restrict__ b, ushort* __restrict__ y){
  int tok = blockIdx.x, t = threadIdx.x;
  const float* xp = x + (size_t)tok*HID;
  float v1 = xp[t], v2 = xp[t + 256];
  __shared__ float red[4];
  float s = v1 + v2;
  #pragma unroll
  for (int off = 32; off; off >>= 1) s += __shfl_xor(s, off);
  if ((t & 63) == 0) red[t >> 6] = s;
  __syncthreads();
  float mean = (red[0] + red[1] + red[2] + red[3]) * (1.0f/512.0f);
  __syncthreads();
  float d1 = v1 - mean, d2 = v2 - mean;
  s = d1*d1 + d2*d2;
  #pragma unroll
  for (int off = 32; off; off >>= 1) s += __shfl_xor(s, off);
  if ((t & 63) == 0) red[t >> 6] = s;
  __syncthreads();
  float var = (red[0] + red[1] + red[2] + red[3]) * (1.0f/512.0f);
  float rs  = rsqrtf(var + 1e-5f);
  ushort* yp = y + (size_t)tok*HID;
  yp[t]       = f2bf(d1*rs*g[t]       + b[t]);
  yp[t + 256] = f2bf(d2*rs*g[t + 256] + b[t + 256]);
}

// ---------------- fused per-head QKV projection (bf16 y in, fp32 out) -------
__global__ __launch_bounds__(512)
void qkv_kernel(const ushort* __restrict__ y,
                const float* __restrict__ Wq, const float* __restrict__ Wk,
                const float* __restrict__ Wv,
                const float* __restrict__ bq, const float* __restrict__ bk,
                const float* __restrict__ bv,
                float* __restrict__ q, float* __restrict__ k,
                float* __restrict__ v){
  const float* W; const float* bias; float* out;
  if (blockIdx.y == 0)      { W = Wq; bias = bq; out = q; }
  else if (blockIdx.y == 1) { W = Wk; bias = bk; out = k; }
  else                      { W = Wv; bias = bv; out = v; }
  int tok0 = blockIdx.x * 8;
  int t = threadIdx.x;
  __shared__ float yl[8*512];
  const ushort4* ysrc = (const ushort4*)(y + (size_t)tok0*HID);
  for (int i = t; i < 1024; i += 512){
    ushort4 u = ysrc[i];
    yl[i*4+0] = bf2f(u.x); yl[i*4+1] = bf2f(u.y);
    yl[i*4+2] = bf2f(u.z); yl[i*4+3] = bf2f(u.w);
  }
  __syncthreads();
  int hh = t >> 6;
  const float4* wr = (const float4*)&W[(size_t)t * 64];
  float4 w4[16];
  #pragma unroll
  for (int j = 0; j < 16; ++j) w4[j] = wr[j];
  float bs = bias[t];
  for (int tk = 0; tk < 8; ++tk){
    const float4* yr = (const float4*)&yl[tk*512 + hh*64];
    float acc = 0.f;
    #pragma unroll
    for (int j = 0; j < 16; ++j){
      float4 yv = yr[j];
      acc += yv.x*w4[j].x + yv.y*w4[j].y + yv.z*w4[j].z + yv.w*w4[j].w;
    }
    out[(size_t)(tok0 + tk)*HID + t] = acc + bs;
  }
}

// ---------------- flash attention + residual add into h ----------------
#define ABLK 32
__global__ __launch_bounds__(256, 2)
void attn_kernel(const float* __restrict__ q, const float* __restrict__ k,
                 const float* __restrict__ v, float* __restrict__ h){
  int nh = blockIdx.x;
  int n  = nh >> 3, hd = nh & 7;
  __shared__ float kl[ABLK*64];
  __shared__ float vl[ABLK*64];
  int t = threadIdx.x;
  int r = t;
  bool active = r < SEQ;
  size_t base = ((size_t)n*SEQ + (active ? r : 0))*HID + hd*64;
  float qreg[64], acc[64];
  if (active){
    #pragma unroll
    for (int d = 0; d < 64; d += 4){
      float4 qv = *(const float4*)&q[base + d];
      qreg[d+0] = qv.x * 0.125f; qreg[d+1] = qv.y * 0.125f;
      qreg[d+2] = qv.z * 0.125f; qreg[d+3] = qv.w * 0.125f;
    }
  }
  #pragma unroll
  for (int d = 0; d < 64; ++d) acc[d] = 0.f;
  float m = -1e30f, l = 0.f;

  for (int j0 = 0; j0 < SEQ; j0 += ABLK){
    int cnt = min(ABLK, SEQ - j0);
    __syncthreads();
    for (int i = t; i < ABLK*64; i += 256){
      int jj = i >> 6, d = i & 63;
      float kv = 0.f, vv = 0.f;
      if (jj < cnt){
        size_t src = ((size_t)n*SEQ + j0 + jj)*HID + hd*64 + d;
        kv = k[src]; vv = v[src];
      }
      kl[i] = kv; vl[i] = vv;
    }
    __syncthreads();
    if (active){
      for (int jj = 0; jj < cnt; ++jj){
        float s0 = 0.f, s1 = 0.f, s2 = 0.f, s3 = 0.f;
        #pragma unroll
        for (int d = 0; d < 64; d += 4){
          s0 += qreg[d+0]*kl[jj*64+d+0];
          s1 += qreg[d+1]*kl[jj*64+d+1];
          s2 += qreg[d+2]*kl[jj*64+d+2];
          s3 += qreg[d+3]*kl[jj*64+d+3];
        }
        float s  = (s0 + s1) + (s2 + s3);
        float mn = fmaxf(m, s);
        float corr = __expf(m - mn);
        float p    = __expf(s - mn);
        l = l*corr + p;
        m = mn;
        #pragma unroll
        for (int d = 0; d < 64; ++d)
          acc[d] = acc[d]*corr + p*vl[jj*64+d];
      }
    }
  }
  if (active){
    float inv = 1.0f / l;
    #pragma unroll
    for (int d = 0; d < 64; ++d)
      h[base + d] += acc[d] * inv;
  }
}

// ---------------- head: logits = h[:,0] @ W + b, softmax ----------------
__global__ __launch_bounds__(256)
void head_kernel(const float* __restrict__ h, const float* __restrict__ W,
                 const float* __restrict__ b, float* __restrict__ out){
  int n = blockIdx.x, t = threadIdx.x;
  __shared__ float hl[512];
  __shared__ float logits[OUTC];
  __shared__ float red[4];
  hl[t]       = h[(size_t)n*SEQ*HID + t];
  hl[t + 256] = h[(size_t)n*SEQ*HID + t + 256];
  __syncthreads();
  for (int j = 0; j < 4; ++j){
    int e = t + j*256;
    if (e < OUTC){
      float a0 = b[e];
      #pragma unroll 4
      for (int kx = 0; kx < 512; ++kx) a0 += hl[kx] * W[(size_t)kx*OUTC + e];
      logits[e] = a0;
    }
  }
  __syncthreads();
  float mx = -1e30f;
  for (int j = 0; j < 4; ++j){ int e = t + j*256; if (e < OUTC) mx = fmaxf(mx, logits[e]); }
  #pragma unroll
  for (int off = 32; off; off >>= 1) mx = fmaxf(mx, __shfl_xor(mx, off));
  if ((t & 63) == 0) red[t >> 6] = mx;
  __syncthreads();
  mx = fmaxf(fmaxf(red[0], red[1]), fmaxf(red[2], red[3]));
  __syncthreads();
  float sum = 0.f;
  for (int j = 0; j < 4; ++j){ int e = t + j*256; if (e < OUTC) sum += expf(logits[e] - mx); }
  #pragma unroll
  for (int off = 32; off; off >>= 1) sum += __shfl_xor(sum, off);
  if ((t & 63) == 0) red[t >> 6] = sum;
  __syncthreads();
  sum = red[0] + red[1] + red[2] + red[3];
  float inv = 1.0f / sum;
  for (int j = 0; j < 4; ++j){
    int e = t + j*256;
    if (e < OUTC) out[(size_t)n*OUTC + e] = expf(logits[e] - mx) * inv;
  }
}

extern "C" void kernel_launch(void* const* d_in, const int* in_sizes, int n_in,
                              void* d_out, int out_size, void* d_ws, size_t ws_size,
                              hipStream_t stream){
  const float* x       = (const float*)d_in[0];
  const float* embed_W = (const float*)d_in[1];
  const float* embed_b = (const float*)d_in[2];
  const float* cls     = (const float*)d_in[3];
  const float* ln1_g   = (const float*)d_in[4];
  const float* ln1_b   = (const float*)d_in[5];
  const float* qW      = (const float*)d_in[6];
  const float* qb      = (const float*)d_in[7];
  const float* kW      = (const float*)d_in[8];
  const float* kb      = (const float*)d_in[9];
  const float* vW      = (const float*)d_in[10];
  const float* vb      = (const float*)d_in[11];
  const float* ln2_g   = (const float*)d_in[12];
  const float* ln2_b   = (const float*)d_in[13];
  const float* mlp1_W  = (const float*)d_in[14];
  const float* mlp1_b  = (const float*)d_in[15];
  const float* mlp2_W  = (const float*)d_in[16];
  const float* mlp2_b  = (const float*)d_in[17];
  const float* head_W  = (const float*)d_in[18];
  const float* head_b  = (const float*)d_in[19];
  float* out = (float*)d_out;

  char* wsb = (char*)d_ws;
  float*  h   = (float*)wsb;                                   // MPAD*512 f32
  ushort* y   = (ushort*)(wsb + (size_t)MPAD*HID*4);           // MPAD*512 bf16
  char*   un  = wsb + (size_t)MPAD*HID*4 + (size_t)MPAD*HID*2; // union region
  float*  q   = (float*)un;                                    // TT*512 f32
  float*  kk  = q  + (size_t)TT*HID;
  float*  vv  = kk + (size_t)TT*HID;
  ushort* z1  = (ushort*)un;                                   // MPAD*2048 bf16 (overlaps qkv)
  ushort* p   = (ushort*)un;                                   // NPTOK*768 bf16 (pre-loop)
  char*   wts = un + (size_t)3*TT*HID*4;
  ushort* w1t = (ushort*)wts;                                  // 20*2048*512
  ushort* w2t = w1t + (size_t)LAY*2048*512;                    // 20*512*2048
  ushort* wet = w2t + (size_t)LAY*2048*512;                    // 512*768

  // weight prep: fp32 [R][C] -> bf16 [C][R]
  convt_kernel<<<dim3(2048/32, 512/32, LAY), 256, 0, stream>>>(mlp1_W, w1t, 512, 2048);
  convt_kernel<<<dim3(512/32, 2048/32, LAY), 256, 0, stream>>>(mlp2_W, w2t, 2048, 512);
  convt_kernel<<<dim3(512/32, 768/32, 1),    256, 0, stream>>>(embed_W, wet, 768, 512);

  patchify_kernel<<<(NPTOK*IN_DIM)/256, 256, 0, stream>>>(x, p);
  cls_kernel<<<BATCH, 512, 0, stream>>>(cls, h);
  gemm_mfma<3><<<dim3(HID/128, NPTOK/128), 256, 0, stream>>>(
      p, wet, embed_b, h, IN_DIM, HID, NPTOK);

  for (int l = 0; l < LAY; ++l){
    ln_kernel<<<TT, 256, 0, stream>>>(h, ln1_g + l*HID, ln1_b + l*HID, y);
    qkv_kernel<<<dim3(TT/8, 3), 512, 0, stream>>>(
        y,
        qW + (size_t)l*NH*DH*DH, kW + (size_t)l*NH*DH*DH, vW + (size_t)l*NH*DH*DH,
        qb + (size_t)l*HID, kb + (size_t)l*HID, vb + (size_t)l*HID,
        q, kk, vv);
    attn_kernel<<<BATCH*NH, 256, 0, stream>>>(q, kk, vv, h);
    ln_kernel<<<TT, 256, 0, stream>>>(h, ln2_g + l*HID, ln2_b + l*HID, y);
    gemm_mfma<1><<<dim3((4*HID)/128, MPAD/128), 256, 0, stream>>>(
        y, w1t + (size_t)l*2048*512, mlp1_b + (size_t)l*4*HID, z1,
        HID, 4*HID, TT);
    gemm_mfma<2><<<dim3(HID/128, MPAD/128), 256, 0, stream>>>(
        z1, w2t + (size_t)l*2048*512, mlp2_b + (size_t)l*HID, h,
        4*HID, HID, TT);
  }

  head_kernel<<<BATCH, 256, 0, stream>>>(h, head_W, head_b, out);
}

// Round 3
// 6401.077 us; speedup vs baseline: 3.6084x; 1.5622x over previous
//
#include <hip/hip_runtime.h>
#include <hip/hip_bf16.h>
#include <math.h>

#define LAY 20
#define HID 512
#define NH 8
#define DH 64
#define OUTC 1000
#define SEQ 197
#define SPAD 224            /* 7 k-tiles of 32 */
#define BATCH 64
#define TT (BATCH*SEQ)      /* 12608 tokens */
#define MPAD 12672          /* 99*128 */
#define NPTOK (BATCH*196)   /* 12544 = 98*128 */
#define IN_DIM 768

typedef __attribute__((ext_vector_type(8))) short bf16x8;
typedef __attribute__((ext_vector_type(4))) float f32x4;

__device__ __forceinline__ ushort f2bf(float f){
  __hip_bfloat16 h = __float2bfloat16(f);
  return *(ushort*)&h;
}
__device__ __forceinline__ float bf2f(ushort u){
  __hip_bfloat16 h = *(__hip_bfloat16*)&u;
  return __bfloat162float(h);
}

__device__ __forceinline__ float posemb(int i, int j){
  float je = (float)(j & ~1);
  float ang = (float)i * powf(10000.0f, -je * (1.0f/(float)HID));
  return (j & 1) ? cosf(ang) : sinf(ang);
}

__device__ __forceinline__ float gelu_exact(float x){
  return 0.5f * x * (1.0f + erff(x * 0.70710678118654752f));
}

__device__ __forceinline__ void gld_lds16(const ushort* g, ushort* l){
  __builtin_amdgcn_global_load_lds((const __attribute__((address_space(1))) void*)g,
                                   (__attribute__((address_space(3))) void*)l, 16, 0, 0);
}

// ------- weight convert+transpose: src fp32 [R][C] -> dst bf16 [C][R] -------
__global__ __launch_bounds__(256)
void convt_kernel(const float* __restrict__ src, ushort* __restrict__ dst,
                  int R, int C){
  __shared__ float tile[32][33];
  const float* s = src + (size_t)blockIdx.z * R * C;
  ushort* d      = dst + (size_t)blockIdx.z * R * C;
  int r0 = blockIdx.y * 32, c0 = blockIdx.x * 32;
  int tc = threadIdx.x & 31, tr = threadIdx.x >> 5;
  #pragma unroll
  for (int i = 0; i < 4; ++i)
    tile[tr + i*8][tc] = s[(size_t)(r0 + tr + i*8)*C + c0 + tc];
  __syncthreads();
  #pragma unroll
  for (int i = 0; i < 4; ++i)
    d[(size_t)(c0 + tr + i*8)*R + r0 + tc] = f2bf(tile[tc][tr + i*8]);
}

// ---------------- patchify ----------------
__global__ __launch_bounds__(256)
void patchify_kernel(const float* __restrict__ x, ushort* __restrict__ p){
  int idx = blockIdx.x * 256 + threadIdx.x;
  int r   = idx / 768, cdx = idx - r * 768;
  int n   = r / 196,  pp  = r - n * 196;
  int pr  = pp / 14,  pc  = pp - pr * 14;
  int c   = cdx >> 8, rem = cdx & 255;
  int ph  = rem >> 4, pw  = rem & 15;
  p[idx] = f2bf(x[ (((size_t)(n*3 + c)*224) + pr*16 + ph)*224 + pc*16 + pw ]);
}

// ---------------- cls row ----------------
__global__ __launch_bounds__(512)
void cls_kernel(const float* __restrict__ cls, float* __restrict__ h){
  int n = blockIdx.x, e = threadIdx.x;
  h[(size_t)n*SEQ*HID + e] = cls[e] + posemb(0, e);
}

// ---------------- MFMA GEMM (unchanged from round 2) ----------------
template<int EPI>
__global__ __launch_bounds__(256)
void gemm_mfma(const ushort* __restrict__ A, const ushort* __restrict__ Bt,
               const float* __restrict__ bias, void* __restrict__ Cv,
               int K, int N, int Mreal){
  __shared__ short As[128*64];
  __shared__ short Bs[128*64];
  int t = threadIdx.x;
  int lane = t & 63, wave = t >> 6;
  int wr = wave >> 1, wc = wave & 1;
  int l16 = lane & 15, lq = lane >> 4;
  int rb = blockIdx.y * 128, cb = blockIdx.x * 128;

  int srow = t >> 3;
  int skoff = (t & 7) * 8;
  const ushort* Ab = A  + (size_t)(rb + srow)*K + skoff;
  const ushort* Bb = Bt + (size_t)(cb + srow)*K + skoff;
  short* Asl = &As[t*8];
  short* Bsl = &Bs[t*8];

  f32x4 acc[4][4];
  #pragma unroll
  for (int m = 0; m < 4; ++m)
    #pragma unroll
    for (int n = 0; n < 4; ++n)
      acc[m][n] = (f32x4){0.f, 0.f, 0.f, 0.f};

  for (int k0 = 0; k0 < K; k0 += 64){
    #pragma unroll
    for (int i = 0; i < 4; ++i){
      gld_lds16((const ushort*)(Ab + (size_t)(i*32)*K + k0), (ushort*)(Asl + i*2048));
      gld_lds16((const ushort*)(Bb + (size_t)(i*32)*K + k0), (ushort*)(Bsl + i*2048));
    }
    __syncthreads();
    #pragma unroll
    for (int kc = 0; kc < 2; ++kc){
      bf16x8 af[4], bfr[4];
      #pragma unroll
      for (int m = 0; m < 4; ++m)
        af[m] = *(bf16x8*)&As[(wr*64 + m*16 + l16)*64 + kc*32 + lq*8];
      #pragma unroll
      for (int n = 0; n < 4; ++n)
        bfr[n] = *(bf16x8*)&Bs[(wc*64 + n*16 + l16)*64 + kc*32 + lq*8];
      #pragma unroll
      for (int m = 0; m < 4; ++m)
        #pragma unroll
        for (int n = 0; n < 4; ++n)
          acc[m][n] = __builtin_amdgcn_mfma_f32_16x16x32_bf16(af[m], bfr[n], acc[m][n], 0, 0, 0);
    }
    __syncthreads();
  }

  #pragma unroll
  for (int m = 0; m < 4; ++m){
    #pragma unroll
    for (int n = 0; n < 4; ++n){
      int col  = cb + wc*64 + n*16 + l16;
      int row0 = rb + wr*64 + m*16 + lq*4;
      float bv = bias[col];
      #pragma unroll
      for (int j = 0; j < 4; ++j){
        int row = row0 + j;
        float val = acc[m][n][j] + bv;
        if (EPI == 1){
          ((ushort*)Cv)[(size_t)row*N + col] = f2bf(gelu_exact(val));
        } else if (EPI == 2){
          if (row < Mreal) ((float*)Cv)[(size_t)row*N + col] += val;
        } else {
          int bn = row / 196, sp = row - bn*196;
          ((float*)Cv)[((size_t)bn*SEQ + 1 + sp)*HID + col] = val + posemb(1 + sp, col);
        }
      }
    }
  }
}

// ---------------- LayerNorm (fp32 in, bf16 out) ----------------
__global__ __launch_bounds__(256)
void ln_kernel(const float* __restrict__ x, const float* __restrict__ g,
               const float* __restrict__ b, ushort* __restrict__ y){
  int tok = blockIdx.x, t = threadIdx.x;
  const float* xp = x + (size_t)tok*HID;
  float v1 = xp[t], v2 = xp[t + 256];
  __shared__ float red[4];
  float s = v1 + v2;
  #pragma unroll
  for (int off = 32; off; off >>= 1) s += __shfl_xor(s, off);
  if ((t & 63) == 0) red[t >> 6] = s;
  __syncthreads();
  float mean = (red[0] + red[1] + red[2] + red[3]) * (1.0f/512.0f);
  __syncthreads();
  float d1 = v1 - mean, d2 = v2 - mean;
  s = d1*d1 + d2*d2;
  #pragma unroll
  for (int off = 32; off; off >>= 1) s += __shfl_xor(s, off);
  if ((t & 63) == 0) red[t >> 6] = s;
  __syncthreads();
  float var = (red[0] + red[1] + red[2] + red[3]) * (1.0f/512.0f);
  float rs  = rsqrtf(var + 1e-5f);
  ushort* yp = y + (size_t)tok*HID;
  yp[t]       = f2bf(d1*rs*g[t]       + b[t]);
  yp[t + 256] = f2bf(d2*rs*g[t + 256] + b[t + 256]);
}

// ---------------- fused per-head QKV projection ----------------
// outputs: q,k bf16 [tok][512]; v transposed bf16 vt[(n*8+h)*64+d][SPAD] at col s
__global__ __launch_bounds__(512)
void qkv_kernel(const ushort* __restrict__ y,
                const float* __restrict__ Wq, const float* __restrict__ Wk,
                const float* __restrict__ Wv,
                const float* __restrict__ bq, const float* __restrict__ bk,
                const float* __restrict__ bv,
                ushort* __restrict__ q, ushort* __restrict__ k,
                ushort* __restrict__ vt){
  const float* W; const float* bias;
  if (blockIdx.y == 0)      { W = Wq; bias = bq; }
  else if (blockIdx.y == 1) { W = Wk; bias = bk; }
  else                      { W = Wv; bias = bv; }
  int tok0 = blockIdx.x * 8;
  int t = threadIdx.x;
  __shared__ float yl[8*512];
  const ushort4* ysrc = (const ushort4*)(y + (size_t)tok0*HID);
  for (int i = t; i < 1024; i += 512){
    ushort4 u = ysrc[i];
    yl[i*4+0] = bf2f(u.x); yl[i*4+1] = bf2f(u.y);
    yl[i*4+2] = bf2f(u.z); yl[i*4+3] = bf2f(u.w);
  }
  __syncthreads();
  int hh = t >> 6;
  const float4* wr = (const float4*)&W[(size_t)t * 64];
  float4 w4[16];
  #pragma unroll
  for (int j = 0; j < 16; ++j) w4[j] = wr[j];
  float bs = bias[t];
  for (int tk = 0; tk < 8; ++tk){
    const float4* yr = (const float4*)&yl[tk*512 + hh*64];
    float acc = 0.f;
    #pragma unroll
    for (int j = 0; j < 16; ++j){
      float4 yv = yr[j];
      acc += yv.x*w4[j].x + yv.y*w4[j].y + yv.z*w4[j].z + yv.w*w4[j].w;
    }
    ushort r = f2bf(acc + bs);
    int tok = tok0 + tk;
    if (blockIdx.y == 0)      q[(size_t)tok*HID + t] = r;
    else if (blockIdx.y == 1) k[(size_t)tok*HID + t] = r;
    else {
      int n = tok / SEQ, s = tok - n*SEQ;
      vt[((size_t)(n*NH + hh)*64 + (t & 63))*SPAD + s] = r;
    }
  }
}

// ---------------- MFMA flash attention + residual add into h ----------------
// 1 block per (n,head), 8 waves x 32 q-rows; K,Vt fully LDS-staged (swizzled)
__global__ __launch_bounds__(512, 4)
void attn_kernel(const ushort* __restrict__ q, const ushort* __restrict__ k,
                 const ushort* __restrict__ vt, float* __restrict__ h){
  __shared__ ushort Ks[SPAD*64];     // [s][64]  swz byte^((s&7)<<4)
  __shared__ ushort Vs[64*256];      // [d][256] swz byte^((d&7)<<4)
  __shared__ ushort Ps[8][32*40];    // per-wave P [32][40] (80B rows)
  int nh = blockIdx.x;
  int n = nh >> 3, hd = nh & 7;
  int t = threadIdx.x;
  int lane = t & 63, wave = t >> 6;
  int l16 = lane & 15, g = lane >> 4;

  // ---- stage K [224][64], rows >=SEQ clamped (masked later) ----
  const ushort* kbase = k + ((size_t)n*SEQ)*HID + hd*64;
  for (int c = t; c < 224*8; c += 512){
    int s = c >> 3, c8 = (c & 7) * 8;
    int sr = s < SEQ ? s : SEQ-1;
    uint4 val = *(const uint4*)&kbase[(size_t)sr*HID + c8];
    int byte = s*128 + c8*2;
    byte ^= (s & 7) << 4;
    *(uint4*)((char*)Ks + byte) = val;
  }
  // ---- stage Vt [64][256], cols >=SEQ forced to zero ----
  const ushort* vbase = vt + (size_t)nh*64*SPAD;
  for (int c = t; c < 64*32; c += 512){
    int d = c >> 5, kc = c & 31;
    uint4 val = {0u,0u,0u,0u};
    if (kc < 24){
      val = *(const uint4*)&vbase[(size_t)d*SPAD + kc*8];
    } else if (kc == 24){
      ushort tmp[8];
      #pragma unroll
      for (int e = 0; e < 8; ++e)
        tmp[e] = (192 + e < SEQ) ? vbase[(size_t)d*SPAD + 192 + e] : (ushort)0;
      val = *(uint4*)tmp;
    }
    int byte = d*512 + kc*16;
    byte ^= (d & 7) << 4;
    *(uint4*)((char*)Vs + byte) = val;
  }

  // ---- Q fragments (global, bf16), rows clamped ----
  int qrow0 = wave * 32;
  bool wactive = qrow0 < SEQ;
  bf16x8 aq[2][2];
  if (wactive){
    #pragma unroll
    for (int m = 0; m < 2; ++m){
      int row = qrow0 + m*16 + l16;
      int sr = row < SEQ ? row : SEQ-1;
      const ushort* qp = q + ((size_t)n*SEQ + sr)*HID + hd*64;
      #pragma unroll
      for (int kc = 0; kc < 2; ++kc)
        aq[m][kc] = *(const bf16x8*)&qp[kc*32 + g*8];
    }
  }
  __syncthreads();

  if (wactive){
    ushort* myP = &Ps[wave][0];
    f32x4 accO[2][4];
    float mrun[2][4], lrun[2][4];
    #pragma unroll
    for (int m = 0; m < 2; ++m){
      #pragma unroll
      for (int nd = 0; nd < 4; ++nd) accO[m][nd] = (f32x4){0.f,0.f,0.f,0.f};
      #pragma unroll
      for (int j = 0; j < 4; ++j){ mrun[m][j] = -1e30f; lrun[m][j] = 0.f; }
    }

    for (int kt = 0; kt < 7; ++kt){
      // ---- S = Q K^T (32q x 32k) ----
      f32x4 accS[2][2];
      #pragma unroll
      for (int m = 0; m < 2; ++m)
        #pragma unroll
        for (int nn = 0; nn < 2; ++nn) accS[m][nn] = (f32x4){0.f,0.f,0.f,0.f};
      #pragma unroll
      for (int kc = 0; kc < 2; ++kc){
        bf16x8 bk[2];
        #pragma unroll
        for (int nn = 0; nn < 2; ++nn){
          int srow = kt*32 + nn*16 + l16;
          int byte = srow*128 + kc*64 + g*16;
          byte ^= (srow & 7) << 4;
          bk[nn] = *(const bf16x8*)((const char*)Ks + byte);
        }
        #pragma unroll
        for (int m = 0; m < 2; ++m)
          #pragma unroll
          for (int nn = 0; nn < 2; ++nn)
            accS[m][nn] = __builtin_amdgcn_mfma_f32_16x16x32_bf16(aq[m][kc], bk[nn], accS[m][nn], 0, 0, 0);
      }
      // ---- online softmax; P -> LDS (bf16) ----
      bool kv0 = (kt*32 + l16) < SEQ;
      bool kv1 = (kt*32 + 16 + l16) < SEQ;
      #pragma unroll
      for (int m = 0; m < 2; ++m){
        #pragma unroll
        for (int j = 0; j < 4; ++j){
          float s0 = kv0 ? accS[m][0][j]*0.125f : -1e30f;
          float s1 = kv1 ? accS[m][1][j]*0.125f : -1e30f;
          float mx = fmaxf(s0, s1);
          mx = fmaxf(mx, __shfl_xor(mx, 1));
          mx = fmaxf(mx, __shfl_xor(mx, 2));
          mx = fmaxf(mx, __shfl_xor(mx, 4));
          mx = fmaxf(mx, __shfl_xor(mx, 8));
          float mold = mrun[m][j];
          float mnew = fmaxf(mold, mx);
          float corr = __expf(mold - mnew);
          mrun[m][j] = mnew;
          float p0 = __expf(s0 - mnew);
          float p1 = __expf(s1 - mnew);
          float rs = p0 + p1;
          rs += __shfl_xor(rs, 1);
          rs += __shfl_xor(rs, 2);
          rs += __shfl_xor(rs, 4);
          rs += __shfl_xor(rs, 8);
          lrun[m][j] = lrun[m][j]*corr + rs;
          #pragma unroll
          for (int nd = 0; nd < 4; ++nd) accO[m][nd][j] *= corr;
          int prow = m*16 + g*4 + j;
          myP[prow*40 + l16]      = f2bf(p0);
          myP[prow*40 + 16 + l16] = f2bf(p1);
        }
      }
      // ---- O += P V  (A=P rows, B=Vt rows) ----
      bf16x8 ap[2], bv[4];
      #pragma unroll
      for (int m = 0; m < 2; ++m)
        ap[m] = *(const bf16x8*)&myP[(m*16 + l16)*40 + g*8];
      #pragma unroll
      for (int nd = 0; nd < 4; ++nd){
        int d = nd*16 + l16;
        int byte = d*512 + kt*64 + g*16;
        byte ^= (d & 7) << 4;
        bv[nd] = *(const bf16x8*)((const char*)Vs + byte);
      }
      #pragma unroll
      for (int m = 0; m < 2; ++m)
        #pragma unroll
        for (int nd = 0; nd < 4; ++nd)
          accO[m][nd] = __builtin_amdgcn_mfma_f32_16x16x32_bf16(ap[m], bv[nd], accO[m][nd], 0, 0, 0);
    }

    // ---- epilogue: h += O / l ----
    #pragma unroll
    for (int m = 0; m < 2; ++m){
      #pragma unroll
      for (int j = 0; j < 4; ++j){
        int row = qrow0 + m*16 + g*4 + j;
        if (row < SEQ){
          float inv = 1.0f / lrun[m][j];
          float* hp = h + ((size_t)n*SEQ + row)*HID + hd*64;
          #pragma unroll
          for (int nd = 0; nd < 4; ++nd)
            hp[nd*16 + l16] += accO[m][nd][j] * inv;
        }
      }
    }
  }
}

// ---------------- head ----------------
__global__ __launch_bounds__(256)
void head_kernel(const float* __restrict__ h, const float* __restrict__ W,
                 const float* __restrict__ b, float* __restrict__ out){
  int n = blockIdx.x, t = threadIdx.x;
  __shared__ float hl[512];
  __shared__ float logits[OUTC];
  __shared__ float red[4];
  hl[t]       = h[(size_t)n*SEQ*HID + t];
  hl[t + 256] = h[(size_t)n*SEQ*HID + t + 256];
  __syncthreads();
  for (int j = 0; j < 4; ++j){
    int e = t + j*256;
    if (e < OUTC){
      float a0 = b[e];
      #pragma unroll 4
      for (int kx = 0; kx < 512; ++kx) a0 += hl[kx] * W[(size_t)kx*OUTC + e];
      logits[e] = a0;
    }
  }
  __syncthreads();
  float mx = -1e30f;
  for (int j = 0; j < 4; ++j){ int e = t + j*256; if (e < OUTC) mx = fmaxf(mx, logits[e]); }
  #pragma unroll
  for (int off = 32; off; off >>= 1) mx = fmaxf(mx, __shfl_xor(mx, off));
  if ((t & 63) == 0) red[t >> 6] = mx;
  __syncthreads();
  mx = fmaxf(fmaxf(red[0], red[1]), fmaxf(red[2], red[3]));
  __syncthreads();
  float sum = 0.f;
  for (int j = 0; j < 4; ++j){ int e = t + j*256; if (e < OUTC) sum += expf(logits[e] - mx); }
  #pragma unroll
  for (int off = 32; off; off >>= 1) sum += __shfl_xor(sum, off);
  if ((t & 63) == 0) red[t >> 6] = sum;
  __syncthreads();
  sum = red[0] + red[1] + red[2] + red[3];
  float inv = 1.0f / sum;
  for (int j = 0; j < 4; ++j){
    int e = t + j*256;
    if (e < OUTC) out[(size_t)n*OUTC + e] = expf(logits[e] - mx) * inv;
  }
}

extern "C" void kernel_launch(void* const* d_in, const int* in_sizes, int n_in,
                              void* d_out, int out_size, void* d_ws, size_t ws_size,
                              hipStream_t stream){
  const float* x       = (const float*)d_in[0];
  const float* embed_W = (const float*)d_in[1];
  const float* embed_b = (const float*)d_in[2];
  const float* cls     = (const float*)d_in[3];
  const float* ln1_g   = (const float*)d_in[4];
  const float* ln1_b   = (const float*)d_in[5];
  const float* qW      = (const float*)d_in[6];
  const float* qb      = (const float*)d_in[7];
  const float* kW      = (const float*)d_in[8];
  const float* kb      = (const float*)d_in[9];
  const float* vW      = (const float*)d_in[10];
  const float* vb      = (const float*)d_in[11];
  const float* ln2_g   = (const float*)d_in[12];
  const float* ln2_b   = (const float*)d_in[13];
  const float* mlp1_W  = (const float*)d_in[14];
  const float* mlp1_b  = (const float*)d_in[15];
  const float* mlp2_W  = (const float*)d_in[16];
  const float* mlp2_b  = (const float*)d_in[17];
  const float* head_W  = (const float*)d_in[18];
  const float* head_b  = (const float*)d_in[19];
  float* out = (float*)d_out;

  char* wsb = (char*)d_ws;
  float*  h   = (float*)wsb;                                   // MPAD*512 f32
  ushort* y   = (ushort*)(wsb + (size_t)MPAD*HID*4);           // MPAD*512 bf16
  char*   un  = wsb + (size_t)MPAD*HID*4 + (size_t)MPAD*HID*2; // union region
  ushort* qb_  = (ushort*)un;                                  // TT*512 bf16
  ushort* kb_  = qb_ + (size_t)TT*HID;                         // TT*512 bf16
  ushort* vtb  = kb_ + (size_t)TT*HID;                         // 512*64*SPAD bf16
  ushort* z1  = (ushort*)un;                                   // MPAD*2048 bf16 (overlaps qkv)
  ushort* p   = (ushort*)un;                                   // patches (pre-loop)
  char*   wts = un + (size_t)3*TT*HID*4;
  ushort* w1t = (ushort*)wts;
  ushort* w2t = w1t + (size_t)LAY*2048*512;
  ushort* wet = w2t + (size_t)LAY*2048*512;

  convt_kernel<<<dim3(2048/32, 512/32, LAY), 256, 0, stream>>>(mlp1_W, w1t, 512, 2048);
  convt_kernel<<<dim3(512/32, 2048/32, LAY), 256, 0, stream>>>(mlp2_W, w2t, 2048, 512);
  convt_kernel<<<dim3(512/32, 768/32, 1),    256, 0, stream>>>(embed_W, wet, 768, 512);

  patchify_kernel<<<(NPTOK*IN_DIM)/256, 256, 0, stream>>>(x, p);
  cls_kernel<<<BATCH, 512, 0, stream>>>(cls, h);
  gemm_mfma<3><<<dim3(HID/128, NPTOK/128), 256, 0, stream>>>(
      p, wet, embed_b, h, IN_DIM, HID, NPTOK);

  for (int l = 0; l < LAY; ++l){
    ln_kernel<<<TT, 256, 0, stream>>>(h, ln1_g + l*HID, ln1_b + l*HID, y);
    qkv_kernel<<<dim3(TT/8, 3), 512, 0, stream>>>(
        y,
        qW + (size_t)l*NH*DH*DH, kW + (size_t)l*NH*DH*DH, vW + (size_t)l*NH*DH*DH,
        qb + (size_t)l*HID, kb + (size_t)l*HID, vb + (size_t)l*HID,
        qb_, kb_, vtb);
    attn_kernel<<<BATCH*NH, 512, 0, stream>>>(qb_, kb_, vtb, h);
    ln_kernel<<<TT, 256, 0, stream>>>(h, ln2_g + l*HID, ln2_b + l*HID, y);
    gemm_mfma<1><<<dim3((4*HID)/128, MPAD/128), 256, 0, stream>>>(
        y, w1t + (size_t)l*2048*512, mlp1_b + (size_t)l*4*HID, z1,
        HID, 4*HID, TT);
    gemm_mfma<2><<<dim3(HID/128, MPAD/128), 256, 0, stream>>>(
        z1, w2t + (size_t)l*2048*512, mlp2_b + (size_t)l*HID, h,
        4*HID, HID, TT);
  }

  head_kernel<<<BATCH, 256, 0, stream>>>(h, head_W, head_b, out);
}

// Round 4
// 4712.487 us; speedup vs baseline: 4.9014x; 1.3583x over previous
//
#include <hip/hip_runtime.h>
#include <hip/hip_bf16.h>
#include <math.h>

#define LAY 20
#define HID 512
#define NH 8
#define DH 64
#define OUTC 1000
#define SEQ 197
#define SPAD 224            /* 7 k-tiles of 32 */
#define BATCH 64
#define TT (BATCH*SEQ)      /* 12608 tokens */
#define MPAD 12672          /* 99*128 */
#define NPTOK (BATCH*196)   /* 12544 = 98*128 */
#define IN_DIM 768

typedef __attribute__((ext_vector_type(8))) short bf16x8;
typedef __attribute__((ext_vector_type(4))) float f32x4;

__device__ __forceinline__ ushort f2bf(float f){
  __hip_bfloat16 h = __float2bfloat16(f);
  return *(ushort*)&h;
}
__device__ __forceinline__ float bf2f(ushort u){
  __hip_bfloat16 h = *(__hip_bfloat16*)&u;
  return __bfloat162float(h);
}

__device__ __forceinline__ float posemb(int i, int j){
  float je = (float)(j & ~1);
  float ang = (float)i * powf(10000.0f, -je * (1.0f/(float)HID));
  return (j & 1) ? cosf(ang) : sinf(ang);
}

__device__ __forceinline__ float gelu_exact(float x){
  return 0.5f * x * (1.0f + erff(x * 0.70710678118654752f));
}

__device__ __forceinline__ void gld_lds16(const ushort* g, ushort* l){
  __builtin_amdgcn_global_load_lds((const __attribute__((address_space(1))) void*)g,
                                   (__attribute__((address_space(3))) void*)l, 16, 0, 0);
}

// ------- weight convert+transpose: src fp32 [R][C] -> dst bf16 [C][R] -------
__global__ __launch_bounds__(256)
void convt_kernel(const float* __restrict__ src, ushort* __restrict__ dst,
                  int R, int C){
  __shared__ float tile[32][33];
  const float* s = src + (size_t)blockIdx.z * R * C;
  ushort* d      = dst + (size_t)blockIdx.z * R * C;
  int r0 = blockIdx.y * 32, c0 = blockIdx.x * 32;
  int tc = threadIdx.x & 31, tr = threadIdx.x >> 5;
  #pragma unroll
  for (int i = 0; i < 4; ++i)
    tile[tr + i*8][tc] = s[(size_t)(r0 + tr + i*8)*C + c0 + tc];
  __syncthreads();
  #pragma unroll
  for (int i = 0; i < 4; ++i)
    d[(size_t)(c0 + tr + i*8)*R + r0 + tc] = f2bf(tile[tc][tr + i*8]);
}

// ------- elementwise fp32 -> bf16 convert -------
__global__ __launch_bounds__(256)
void cvt_kernel(const float* __restrict__ src, ushort* __restrict__ dst, int count){
  int idx = blockIdx.x * 256 + threadIdx.x;
  if (idx < count) dst[idx] = f2bf(src[idx]);
}

// ---------------- patchify ----------------
__global__ __launch_bounds__(256)
void patchify_kernel(const float* __restrict__ x, ushort* __restrict__ p){
  int idx = blockIdx.x * 256 + threadIdx.x;
  int r   = idx / 768, cdx = idx - r * 768;
  int n   = r / 196,  pp  = r - n * 196;
  int pr  = pp / 14,  pc  = pp - pr * 14;
  int c   = cdx >> 8, rem = cdx & 255;
  int ph  = rem >> 4, pw  = rem & 15;
  p[idx] = f2bf(x[ (((size_t)(n*3 + c)*224) + pr*16 + ph)*224 + pc*16 + pw ]);
}

// ---------------- cls row ----------------
__global__ __launch_bounds__(512)
void cls_kernel(const float* __restrict__ cls, float* __restrict__ h){
  int n = blockIdx.x, e = threadIdx.x;
  h[(size_t)n*SEQ*HID + e] = cls[e] + posemb(0, e);
}

// ---------------- MFMA GEMM ----------------
template<int EPI>
__global__ __launch_bounds__(256)
void gemm_mfma(const ushort* __restrict__ A, const ushort* __restrict__ Bt,
               const float* __restrict__ bias, void* __restrict__ Cv,
               int K, int N, int Mreal){
  __shared__ short As[128*64];
  __shared__ short Bs[128*64];
  int t = threadIdx.x;
  int lane = t & 63, wave = t >> 6;
  int wr = wave >> 1, wc = wave & 1;
  int l16 = lane & 15, lq = lane >> 4;
  int rb = blockIdx.y * 128, cb = blockIdx.x * 128;

  int srow = t >> 3;
  int skoff = (t & 7) * 8;
  const ushort* Ab = A  + (size_t)(rb + srow)*K + skoff;
  const ushort* Bb = Bt + (size_t)(cb + srow)*K + skoff;
  short* Asl = &As[t*8];
  short* Bsl = &Bs[t*8];

  f32x4 acc[4][4];
  #pragma unroll
  for (int m = 0; m < 4; ++m)
    #pragma unroll
    for (int n = 0; n < 4; ++n)
      acc[m][n] = (f32x4){0.f, 0.f, 0.f, 0.f};

  for (int k0 = 0; k0 < K; k0 += 64){
    #pragma unroll
    for (int i = 0; i < 4; ++i){
      gld_lds16((const ushort*)(Ab + (size_t)(i*32)*K + k0), (ushort*)(Asl + i*2048));
      gld_lds16((const ushort*)(Bb + (size_t)(i*32)*K + k0), (ushort*)(Bsl + i*2048));
    }
    __syncthreads();
    #pragma unroll
    for (int kc = 0; kc < 2; ++kc){
      bf16x8 af[4], bfr[4];
      #pragma unroll
      for (int m = 0; m < 4; ++m)
        af[m] = *(bf16x8*)&As[(wr*64 + m*16 + l16)*64 + kc*32 + lq*8];
      #pragma unroll
      for (int n = 0; n < 4; ++n)
        bfr[n] = *(bf16x8*)&Bs[(wc*64 + n*16 + l16)*64 + kc*32 + lq*8];
      #pragma unroll
      for (int m = 0; m < 4; ++m)
        #pragma unroll
        for (int n = 0; n < 4; ++n)
          acc[m][n] = __builtin_amdgcn_mfma_f32_16x16x32_bf16(af[m], bfr[n], acc[m][n], 0, 0, 0);
    }
    __syncthreads();
  }

  #pragma unroll
  for (int m = 0; m < 4; ++m){
    #pragma unroll
    for (int n = 0; n < 4; ++n){
      int col  = cb + wc*64 + n*16 + l16;
      int row0 = rb + wr*64 + m*16 + lq*4;
      float bv = bias[col];
      #pragma unroll
      for (int j = 0; j < 4; ++j){
        int row = row0 + j;
        float val = acc[m][n][j] + bv;
        if (EPI == 1){
          ((ushort*)Cv)[(size_t)row*N + col] = f2bf(gelu_exact(val));
        } else if (EPI == 2){
          if (row < Mreal) ((float*)Cv)[(size_t)row*N + col] += val;
        } else {
          int bn = row / 196, sp = row - bn*196;
          ((float*)Cv)[((size_t)bn*SEQ + 1 + sp)*HID + col] = val + posemb(1 + sp, col);
        }
      }
    }
  }
}

// ---------------- LayerNorm (fp32 in, bf16 out) ----------------
__global__ __launch_bounds__(256)
void ln_kernel(const float* __restrict__ x, const float* __restrict__ g,
               const float* __restrict__ b, ushort* __restrict__ y){
  int tok = blockIdx.x, t = threadIdx.x;
  const float* xp = x + (size_t)tok*HID;
  float v1 = xp[t], v2 = xp[t + 256];
  __shared__ float red[4];
  float s = v1 + v2;
  #pragma unroll
  for (int off = 32; off; off >>= 1) s += __shfl_xor(s, off);
  if ((t & 63) == 0) red[t >> 6] = s;
  __syncthreads();
  float mean = (red[0] + red[1] + red[2] + red[3]) * (1.0f/512.0f);
  __syncthreads();
  float d1 = v1 - mean, d2 = v2 - mean;
  s = d1*d1 + d2*d2;
  #pragma unroll
  for (int off = 32; off; off >>= 1) s += __shfl_xor(s, off);
  if ((t & 63) == 0) red[t >> 6] = s;
  __syncthreads();
  float var = (red[0] + red[1] + red[2] + red[3]) * (1.0f/512.0f);
  float rs  = rsqrtf(var + 1e-5f);
  ushort* yp = y + (size_t)tok*HID;
  yp[t]       = f2bf(d1*rs*g[t]       + b[t]);
  yp[t + 256] = f2bf(d2*rs*g[t + 256] + b[t + 256]);
}

// ---------------- MFMA QKV projection (per-head block-diagonal GEMM) -------
// grid (MPAD/128, 24): y-dim = proj*8 + head. A = y[128 rows][h*64..+64),
// Bt = W[h] (64 out x 64 in, K-contiguous). Outputs q,k bf16 rows; v scattered
// transposed into vt[(n*8+h)*64+e][s].
__global__ __launch_bounds__(256)
void qkv_mfma(const ushort* __restrict__ y,
              const ushort* __restrict__ wqb, const ushort* __restrict__ wkb,
              const ushort* __restrict__ wvb,
              const float* __restrict__ bq, const float* __restrict__ bk,
              const float* __restrict__ bv,
              ushort* __restrict__ q, ushort* __restrict__ k,
              ushort* __restrict__ vt){
  __shared__ short As[128*64];
  __shared__ short Bs[64*64];
  int t = threadIdx.x;
  int lane = t & 63, wave = t >> 6;
  int l16 = lane & 15, g = lane >> 4;
  int p  = blockIdx.y >> 3, hh = blockIdx.y & 7;
  int rb = blockIdx.x * 128;

  const ushort* W; const float* bias;
  if (p == 0)      { W = wqb; bias = bq; }
  else if (p == 1) { W = wkb; bias = bk; }
  else             { W = wvb; bias = bv; }
  W    += (size_t)hh * 64 * 64;
  bias += hh * 64;

  int srow = t >> 3, skoff = (t & 7) * 8;
  const ushort* Ab = y + (size_t)(rb + srow)*HID + hh*64 + skoff;
  const ushort* Bb = W + (size_t)srow*64 + skoff;
  #pragma unroll
  for (int i = 0; i < 4; ++i)
    gld_lds16(Ab + (size_t)(i*32)*HID, (ushort*)&As[t*8 + i*2048]);
  #pragma unroll
  for (int i = 0; i < 2; ++i)
    gld_lds16(Bb + (size_t)(i*32)*64, (ushort*)&Bs[t*8 + i*2048]);
  __syncthreads();

  f32x4 acc[2][4];
  #pragma unroll
  for (int m = 0; m < 2; ++m)
    #pragma unroll
    for (int n = 0; n < 4; ++n)
      acc[m][n] = (f32x4){0.f,0.f,0.f,0.f};

  #pragma unroll
  for (int kc = 0; kc < 2; ++kc){
    bf16x8 af[2], bfr[4];
    #pragma unroll
    for (int m = 0; m < 2; ++m)
      af[m] = *(bf16x8*)&As[(wave*32 + m*16 + l16)*64 + kc*32 + g*8];
    #pragma unroll
    for (int n = 0; n < 4; ++n)
      bfr[n] = *(bf16x8*)&Bs[(n*16 + l16)*64 + kc*32 + g*8];
    #pragma unroll
    for (int m = 0; m < 2; ++m)
      #pragma unroll
      for (int n = 0; n < 4; ++n)
        acc[m][n] = __builtin_amdgcn_mfma_f32_16x16x32_bf16(af[m], bfr[n], acc[m][n], 0, 0, 0);
  }

  #pragma unroll
  for (int m = 0; m < 2; ++m){
    #pragma unroll
    for (int nd = 0; nd < 4; ++nd){
      int e = nd*16 + l16;
      float bv2 = bias[e];
      #pragma unroll
      for (int j = 0; j < 4; ++j){
        int tok = rb + wave*32 + m*16 + g*4 + j;
        if (tok < TT){
          ushort r = f2bf(acc[m][nd][j] + bv2);
          if (p == 0)      q[(size_t)tok*HID + hh*64 + e] = r;
          else if (p == 1) k[(size_t)tok*HID + hh*64 + e] = r;
          else {
            int n = tok / SEQ, s = tok - n*SEQ;
            vt[((size_t)(n*NH + hh)*64 + e)*SPAD + s] = r;
          }
        }
      }
    }
  }
}

// ---------------- MFMA flash attention + residual add into h ----------------
__global__ __launch_bounds__(512, 4)
void attn_kernel(const ushort* __restrict__ q, const ushort* __restrict__ k,
                 const ushort* __restrict__ vt, float* __restrict__ h){
  __shared__ ushort Ks[SPAD*64];     // [s][64]  swz byte^((s&7)<<4)
  __shared__ ushort Vs[64*256];      // [d][256] swz byte^((d&7)<<4)
  __shared__ ushort Ps[8][32*40];    // per-wave P [32][40]
  int nh = blockIdx.x;
  int n = nh >> 3, hd = nh & 7;
  int t = threadIdx.x;
  int lane = t & 63, wave = t >> 6;
  int l16 = lane & 15, g = lane >> 4;

  const ushort* kbase = k + ((size_t)n*SEQ)*HID + hd*64;
  for (int c = t; c < 224*8; c += 512){
    int s = c >> 3, c8 = (c & 7) * 8;
    int sr = s < SEQ ? s : SEQ-1;
    uint4 val = *(const uint4*)&kbase[(size_t)sr*HID + c8];
    int byte = s*128 + c8*2;
    byte ^= (s & 7) << 4;
    *(uint4*)((char*)Ks + byte) = val;
  }
  const ushort* vbase = vt + (size_t)nh*64*SPAD;
  for (int c = t; c < 64*32; c += 512){
    int d = c >> 5, kc = c & 31;
    uint4 val = {0u,0u,0u,0u};
    if (kc < 24){
      val = *(const uint4*)&vbase[(size_t)d*SPAD + kc*8];
    } else if (kc == 24){
      ushort tmp[8];
      #pragma unroll
      for (int e = 0; e < 8; ++e)
        tmp[e] = (192 + e < SEQ) ? vbase[(size_t)d*SPAD + 192 + e] : (ushort)0;
      val = *(uint4*)tmp;
    }
    int byte = d*512 + kc*16;
    byte ^= (d & 7) << 4;
    *(uint4*)((char*)Vs + byte) = val;
  }

  int qrow0 = wave * 32;
  bool wactive = qrow0 < SEQ;
  bf16x8 aq[2][2];
  if (wactive){
    #pragma unroll
    for (int m = 0; m < 2; ++m){
      int row = qrow0 + m*16 + l16;
      int sr = row < SEQ ? row : SEQ-1;
      const ushort* qp = q + ((size_t)n*SEQ + sr)*HID + hd*64;
      #pragma unroll
      for (int kc = 0; kc < 2; ++kc)
        aq[m][kc] = *(const bf16x8*)&qp[kc*32 + g*8];
    }
  }
  __syncthreads();

  if (wactive){
    ushort* myP = &Ps[wave][0];
    f32x4 accO[2][4];
    float mrun[2][4], lrun[2][4];
    #pragma unroll
    for (int m = 0; m < 2; ++m){
      #pragma unroll
      for (int nd = 0; nd < 4; ++nd) accO[m][nd] = (f32x4){0.f,0.f,0.f,0.f};
      #pragma unroll
      for (int j = 0; j < 4; ++j){ mrun[m][j] = -1e30f; lrun[m][j] = 0.f; }
    }

    for (int kt = 0; kt < 7; ++kt){
      f32x4 accS[2][2];
      #pragma unroll
      for (int m = 0; m < 2; ++m)
        #pragma unroll
        for (int nn = 0; nn < 2; ++nn) accS[m][nn] = (f32x4){0.f,0.f,0.f,0.f};
      #pragma unroll
      for (int kc = 0; kc < 2; ++kc){
        bf16x8 bk[2];
        #pragma unroll
        for (int nn = 0; nn < 2; ++nn){
          int srow = kt*32 + nn*16 + l16;
          int byte = srow*128 + kc*64 + g*16;
          byte ^= (srow & 7) << 4;
          bk[nn] = *(const bf16x8*)((const char*)Ks + byte);
        }
        #pragma unroll
        for (int m = 0; m < 2; ++m)
          #pragma unroll
          for (int nn = 0; nn < 2; ++nn)
            accS[m][nn] = __builtin_amdgcn_mfma_f32_16x16x32_bf16(aq[m][kc], bk[nn], accS[m][nn], 0, 0, 0);
      }
      bool kv0 = (kt*32 + l16) < SEQ;
      bool kv1 = (kt*32 + 16 + l16) < SEQ;
      #pragma unroll
      for (int m = 0; m < 2; ++m){
        #pragma unroll
        for (int j = 0; j < 4; ++j){
          float s0 = kv0 ? accS[m][0][j]*0.125f : -1e30f;
          float s1 = kv1 ? accS[m][1][j]*0.125f : -1e30f;
          float mx = fmaxf(s0, s1);
          mx = fmaxf(mx, __shfl_xor(mx, 1));
          mx = fmaxf(mx, __shfl_xor(mx, 2));
          mx = fmaxf(mx, __shfl_xor(mx, 4));
          mx = fmaxf(mx, __shfl_xor(mx, 8));
          float mold = mrun[m][j];
          float mnew = fmaxf(mold, mx);
          float corr = __expf(mold - mnew);
          mrun[m][j] = mnew;
          float p0 = __expf(s0 - mnew);
          float p1 = __expf(s1 - mnew);
          float rs = p0 + p1;
          rs += __shfl_xor(rs, 1);
          rs += __shfl_xor(rs, 2);
          rs += __shfl_xor(rs, 4);
          rs += __shfl_xor(rs, 8);
          lrun[m][j] = lrun[m][j]*corr + rs;
          #pragma unroll
          for (int nd = 0; nd < 4; ++nd) accO[m][nd][j] *= corr;
          int prow = m*16 + g*4 + j;
          myP[prow*40 + l16]      = f2bf(p0);
          myP[prow*40 + 16 + l16] = f2bf(p1);
        }
      }
      bf16x8 ap[2], bv[4];
      #pragma unroll
      for (int m = 0; m < 2; ++m)
        ap[m] = *(const bf16x8*)&myP[(m*16 + l16)*40 + g*8];
      #pragma unroll
      for (int nd = 0; nd < 4; ++nd){
        int d = nd*16 + l16;
        int byte = d*512 + kt*64 + g*16;
        byte ^= (d & 7) << 4;
        bv[nd] = *(const bf16x8*)((const char*)Vs + byte);
      }
      #pragma unroll
      for (int m = 0; m < 2; ++m)
        #pragma unroll
        for (int nd = 0; nd < 4; ++nd)
          accO[m][nd] = __builtin_amdgcn_mfma_f32_16x16x32_bf16(ap[m], bv[nd], accO[m][nd], 0, 0, 0);
    }

    #pragma unroll
    for (int m = 0; m < 2; ++m){
      #pragma unroll
      for (int j = 0; j < 4; ++j){
        int row = qrow0 + m*16 + g*4 + j;
        if (row < SEQ){
          float inv = 1.0f / lrun[m][j];
          float* hp = h + ((size_t)n*SEQ + row)*HID + hd*64;
          #pragma unroll
          for (int nd = 0; nd < 4; ++nd)
            hp[nd*16 + l16] += accO[m][nd][j] * inv;
        }
      }
    }
  }
}

// ---------------- head stage 1: logits[64][1000] ----------------
// grid 125 blocks; block handles 8 output cols for all 64 samples.
__global__ __launch_bounds__(256)
void head_logits(const float* __restrict__ h, const float* __restrict__ W,
                 const float* __restrict__ b, float* __restrict__ logits){
  int c0 = blockIdx.x * 8;
  __shared__ float Ws[512*8];
  int t = threadIdx.x;
  for (int i = t; i < 512*8; i += 256){
    int kx = i >> 3, c = i & 7;
    Ws[i] = W[(size_t)kx*OUTC + c0 + c];
  }
  __syncthreads();
  int n = t >> 2, g = t & 3;
  const float* hp = h + (size_t)n*SEQ*HID + g*128;
  float acc[8] = {};
  for (int kx = 0; kx < 128; ++kx){
    float hv = hp[kx];
    const float* wsr = &Ws[(g*128 + kx)*8];
    #pragma unroll
    for (int c = 0; c < 8; ++c) acc[c] += hv * wsr[c];
  }
  #pragma unroll
  for (int c = 0; c < 8; ++c){
    acc[c] += __shfl_xor(acc[c], 1);
    acc[c] += __shfl_xor(acc[c], 2);
  }
  if (g == 0){
    #pragma unroll
    for (int c = 0; c < 8; ++c)
      logits[(size_t)n*OUTC + c0 + c] = acc[c] + b[c0 + c];
  }
}

// ---------------- head stage 2: per-sample softmax ----------------
__global__ __launch_bounds__(256)
void head_softmax(const float* __restrict__ logits, float* __restrict__ out){
  int n = blockIdx.x, t = threadIdx.x;
  __shared__ float red[4];
  float v[4];
  #pragma unroll
  for (int j = 0; j < 4; ++j){
    int e = t + j*256;
    v[j] = (e < OUTC) ? logits[(size_t)n*OUTC + e] : -1e30f;
  }
  float mx = fmaxf(fmaxf(v[0], v[1]), fmaxf(v[2], v[3]));
  #pragma unroll
  for (int off = 32; off; off >>= 1) mx = fmaxf(mx, __shfl_xor(mx, off));
  if ((t & 63) == 0) red[t >> 6] = mx;
  __syncthreads();
  mx = fmaxf(fmaxf(red[0], red[1]), fmaxf(red[2], red[3]));
  __syncthreads();
  float sum = 0.f;
  #pragma unroll
  for (int j = 0; j < 4; ++j){ v[j] = __expf(v[j] - mx); sum += v[j]; }
  #pragma unroll
  for (int off = 32; off; off >>= 1) sum += __shfl_xor(sum, off);
  if ((t & 63) == 0) red[t >> 6] = sum;
  __syncthreads();
  sum = red[0] + red[1] + red[2] + red[3];
  float inv = 1.0f / sum;
  #pragma unroll
  for (int j = 0; j < 4; ++j){
    int e = t + j*256;
    if (e < OUTC) out[(size_t)n*OUTC + e] = v[j] * inv;
  }
}

extern "C" void kernel_launch(void* const* d_in, const int* in_sizes, int n_in,
                              void* d_out, int out_size, void* d_ws, size_t ws_size,
                              hipStream_t stream){
  const float* x       = (const float*)d_in[0];
  const float* embed_W = (const float*)d_in[1];
  const float* embed_b = (const float*)d_in[2];
  const float* cls     = (const float*)d_in[3];
  const float* ln1_g   = (const float*)d_in[4];
  const float* ln1_b   = (const float*)d_in[5];
  const float* qW      = (const float*)d_in[6];
  const float* qb      = (const float*)d_in[7];
  const float* kW      = (const float*)d_in[8];
  const float* kb      = (const float*)d_in[9];
  const float* vW      = (const float*)d_in[10];
  const float* vb      = (const float*)d_in[11];
  const float* ln2_g   = (const float*)d_in[12];
  const float* ln2_b   = (const float*)d_in[13];
  const float* mlp1_W  = (const float*)d_in[14];
  const float* mlp1_b  = (const float*)d_in[15];
  const float* mlp2_W  = (const float*)d_in[16];
  const float* mlp2_b  = (const float*)d_in[17];
  const float* head_W  = (const float*)d_in[18];
  const float* head_b  = (const float*)d_in[19];
  float* out = (float*)d_out;

  char* wsb = (char*)d_ws;
  float*  h   = (float*)wsb;                                   // MPAD*512 f32
  ushort* y   = (ushort*)(wsb + (size_t)MPAD*HID*4);           // MPAD*512 bf16
  float*  logits = (float*)y;                                  // head stage (after loop, y free)
  char*   un  = wsb + (size_t)MPAD*HID*4 + (size_t)MPAD*HID*2; // union region
  ushort* qb_  = (ushort*)un;                                  // TT*512 bf16
  ushort* kb_  = qb_ + (size_t)TT*HID;                         // TT*512 bf16
  ushort* vtb  = kb_ + (size_t)TT*HID;                         // 512*64*SPAD bf16
  ushort* z1  = (ushort*)un;                                   // MPAD*2048 bf16 (overlaps qkv)
  ushort* p   = (ushort*)un;                                   // patches (pre-loop)
  char*   wts = un + (size_t)3*TT*HID*4;
  ushort* w1t = (ushort*)wts;                                  // 20*2048*512
  ushort* w2t = w1t + (size_t)LAY*2048*512;                    // 20*512*2048
  ushort* wet = w2t + (size_t)LAY*2048*512;                    // 768*512
  ushort* wqb = wet + (size_t)IN_DIM*HID;                      // 20*8*64*64
  ushort* wkb = wqb + (size_t)LAY*NH*DH*DH;
  ushort* wvb = wkb + (size_t)LAY*NH*DH*DH;

  convt_kernel<<<dim3(2048/32, 512/32, LAY), 256, 0, stream>>>(mlp1_W, w1t, 512, 2048);
  convt_kernel<<<dim3(512/32, 2048/32, LAY), 256, 0, stream>>>(mlp2_W, w2t, 2048, 512);
  convt_kernel<<<dim3(512/32, 768/32, 1),    256, 0, stream>>>(embed_W, wet, 768, 512);
  {
    int cnt = LAY*NH*DH*DH;
    int grd = (cnt + 255)/256;
    cvt_kernel<<<grd, 256, 0, stream>>>(qW, wqb, cnt);
    cvt_kernel<<<grd, 256, 0, stream>>>(kW, wkb, cnt);
    cvt_kernel<<<grd, 256, 0, stream>>>(vW, wvb, cnt);
  }

  patchify_kernel<<<(NPTOK*IN_DIM)/256, 256, 0, stream>>>(x, p);
  cls_kernel<<<BATCH, 512, 0, stream>>>(cls, h);
  gemm_mfma<3><<<dim3(HID/128, NPTOK/128), 256, 0, stream>>>(
      p, wet, embed_b, h, IN_DIM, HID, NPTOK);

  for (int l = 0; l < LAY; ++l){
    ln_kernel<<<TT, 256, 0, stream>>>(h, ln1_g + l*HID, ln1_b + l*HID, y);
    qkv_mfma<<<dim3(MPAD/128, 24), 256, 0, stream>>>(
        y,
        wqb + (size_t)l*NH*DH*DH, wkb + (size_t)l*NH*DH*DH, wvb + (size_t)l*NH*DH*DH,
        qb + (size_t)l*HID, kb + (size_t)l*HID, vb + (size_t)l*HID,
        qb_, kb_, vtb);
    attn_kernel<<<BATCH*NH, 512, 0, stream>>>(qb_, kb_, vtb, h);
    ln_kernel<<<TT, 256, 0, stream>>>(h, ln2_g + l*HID, ln2_b + l*HID, y);
    gemm_mfma<1><<<dim3((4*HID)/128, MPAD/128), 256, 0, stream>>>(
        y, w1t + (size_t)l*2048*512, mlp1_b + (size_t)l*4*HID, z1,
        HID, 4*HID, TT);
    gemm_mfma<2><<<dim3(HID/128, MPAD/128), 256, 0, stream>>>(
        z1, w2t + (size_t)l*2048*512, mlp2_b + (size_t)l*HID, h,
        4*HID, HID, TT);
  }

  head_logits<<<125, 256, 0, stream>>>(h, head_W, head_b, logits);
  head_softmax<<<BATCH, 256, 0, stream>>>(logits, out);
}

// Round 5
// 4187.914 us; speedup vs baseline: 5.5153x; 1.1253x over previous
//
#include <hip/hip_runtime.h>
#include <hip/hip_bf16.h>
#include <math.h>

#define LAY 20
#define HID 512
#define NH 8
#define DH 64
#define OUTC 1000
#define SEQ 197
#define SPAD 224            /* 7 k-tiles of 32 */
#define BATCH 64
#define TT (BATCH*SEQ)      /* 12608 tokens */
#define M2 12800            /* 50*256 = 100*128 */
#define NPTOK (BATCH*196)   /* 12544 = 98*128 */
#define IN_DIM 768

typedef __attribute__((ext_vector_type(8))) short bf16x8;
typedef __attribute__((ext_vector_type(4))) float f32x4;

__device__ __forceinline__ ushort f2bf(float f){
  __hip_bfloat16 h = __float2bfloat16(f);
  return *(ushort*)&h;
}
__device__ __forceinline__ float bf2f(ushort u){
  __hip_bfloat16 h = *(__hip_bfloat16*)&u;
  return __bfloat162float(h);
}

__device__ __forceinline__ float posemb(int i, int j){
  float je = (float)(j & ~1);
  float ang = (float)i * powf(10000.0f, -je * (1.0f/(float)HID));
  return (j & 1) ? cosf(ang) : sinf(ang);
}

__device__ __forceinline__ float gelu_exact(float x){
  return 0.5f * x * (1.0f + erff(x * 0.70710678118654752f));
}

__device__ __forceinline__ void gld_lds16(const ushort* g, ushort* l){
  __builtin_amdgcn_global_load_lds((const __attribute__((address_space(1))) void*)g,
                                   (__attribute__((address_space(3))) void*)l, 16, 0, 0);
}

// ------- weight convert+transpose: src fp32 [R][C] -> dst bf16 [C][R] -------
__global__ __launch_bounds__(256)
void convt_kernel(const float* __restrict__ src, ushort* __restrict__ dst,
                  int R, int C){
  __shared__ float tile[32][33];
  const float* s = src + (size_t)blockIdx.z * R * C;
  ushort* d      = dst + (size_t)blockIdx.z * R * C;
  int r0 = blockIdx.y * 32, c0 = blockIdx.x * 32;
  int tc = threadIdx.x & 31, tr = threadIdx.x >> 5;
  #pragma unroll
  for (int i = 0; i < 4; ++i)
    tile[tr + i*8][tc] = s[(size_t)(r0 + tr + i*8)*C + c0 + tc];
  __syncthreads();
  #pragma unroll
  for (int i = 0; i < 4; ++i)
    d[(size_t)(c0 + tr + i*8)*R + r0 + tc] = f2bf(tile[tc][tr + i*8]);
}

// ------- elementwise fp32 -> bf16 convert -------
__global__ __launch_bounds__(256)
void cvt_kernel(const float* __restrict__ src, ushort* __restrict__ dst, int count){
  int idx = blockIdx.x * 256 + threadIdx.x;
  if (idx < count) dst[idx] = f2bf(src[idx]);
}

// ---------------- patchify ----------------
__global__ __launch_bounds__(256)
void patchify_kernel(const float* __restrict__ x, ushort* __restrict__ p){
  int idx = blockIdx.x * 256 + threadIdx.x;
  int r   = idx / 768, cdx = idx - r * 768;
  int n   = r / 196,  pp  = r - n * 196;
  int pr  = pp / 14,  pc  = pp - pr * 14;
  int c   = cdx >> 8, rem = cdx & 255;
  int ph  = rem >> 4, pw  = rem & 15;
  p[idx] = f2bf(x[ (((size_t)(n*3 + c)*224) + pr*16 + ph)*224 + pc*16 + pw ]);
}

// ---------------- cls row ----------------
__global__ __launch_bounds__(512)
void cls_kernel(const float* __restrict__ cls, float* __restrict__ h){
  int n = blockIdx.x, e = threadIdx.x;
  h[(size_t)n*SEQ*HID + e] = cls[e] + posemb(0, e);
}

// ---------------- old-style MFMA GEMM (embed only, EPI=3) ----------------
template<int EPI>
__global__ __launch_bounds__(256)
void gemm_mfma(const ushort* __restrict__ A, const ushort* __restrict__ Bt,
               const float* __restrict__ bias, void* __restrict__ Cv,
               int K, int N, int Mreal){
  __shared__ short As[128*64];
  __shared__ short Bs[128*64];
  int t = threadIdx.x;
  int lane = t & 63, wave = t >> 6;
  int wr = wave >> 1, wc = wave & 1;
  int l16 = lane & 15, lq = lane >> 4;
  int rb = blockIdx.y * 128, cb = blockIdx.x * 128;

  int srow = t >> 3;
  int skoff = (t & 7) * 8;
  const ushort* Ab = A  + (size_t)(rb + srow)*K + skoff;
  const ushort* Bb = Bt + (size_t)(cb + srow)*K + skoff;
  short* Asl = &As[t*8];
  short* Bsl = &Bs[t*8];

  f32x4 acc[4][4];
  #pragma unroll
  for (int m = 0; m < 4; ++m)
    #pragma unroll
    for (int n = 0; n < 4; ++n)
      acc[m][n] = (f32x4){0.f, 0.f, 0.f, 0.f};

  for (int k0 = 0; k0 < K; k0 += 64){
    #pragma unroll
    for (int i = 0; i < 4; ++i){
      gld_lds16((const ushort*)(Ab + (size_t)(i*32)*K + k0), (ushort*)(Asl + i*2048));
      gld_lds16((const ushort*)(Bb + (size_t)(i*32)*K + k0), (ushort*)(Bsl + i*2048));
    }
    __syncthreads();
    #pragma unroll
    for (int kc = 0; kc < 2; ++kc){
      bf16x8 af[4], bfr[4];
      #pragma unroll
      for (int m = 0; m < 4; ++m)
        af[m] = *(bf16x8*)&As[(wr*64 + m*16 + l16)*64 + kc*32 + lq*8];
      #pragma unroll
      for (int n = 0; n < 4; ++n)
        bfr[n] = *(bf16x8*)&Bs[(wc*64 + n*16 + l16)*64 + kc*32 + lq*8];
      #pragma unroll
      for (int m = 0; m < 4; ++m)
        #pragma unroll
        for (int n = 0; n < 4; ++n)
          acc[m][n] = __builtin_amdgcn_mfma_f32_16x16x32_bf16(af[m], bfr[n], acc[m][n], 0, 0, 0);
    }
    __syncthreads();
  }

  #pragma unroll
  for (int m = 0; m < 4; ++m){
    #pragma unroll
    for (int n = 0; n < 4; ++n){
      int col  = cb + wc*64 + n*16 + l16;
      int row0 = rb + wr*64 + m*16 + lq*4;
      float bv = bias[col];
      #pragma unroll
      for (int j = 0; j < 4; ++j){
        int row = row0 + j;
        float val = acc[m][n][j] + bv;
        if (EPI == 1){
          ((ushort*)Cv)[(size_t)row*N + col] = f2bf(gelu_exact(val));
        } else if (EPI == 2){
          if (row < Mreal) ((float*)Cv)[(size_t)row*N + col] += val;
        } else {
          int bn = row / 196, sp = row - bn*196;
          ((float*)Cv)[((size_t)bn*SEQ + 1 + sp)*HID + col] = val + posemb(1 + sp, col);
        }
      }
    }
  }
}

// ---------------- pipelined MFMA GEMM (MLP) ----------------
// BM=BN=THREADS/2, BK=64, double-buffered LDS, 4 phases per K-tile:
// each phase: {stage 1/4 of next tile (2 gld_lds) || ds_read quad frags ||
// MFMA cluster in setprio(1)}, raw barriers, counted vmcnt(2) at phase 0.
// LDS XOR-swizzle slot^=(row&7) applied to global source AND ds_read.
// EPI: 1 = bias+GELU -> bf16; 2 = bias + add into fp32 C rows<Mreal.
template<int BM, int WM, int WN, int EPI>
__global__ __launch_bounds__(WM*WN*64, 2)
void gemm_pipe(const ushort* __restrict__ A, const ushort* __restrict__ Bt,
               const float* __restrict__ bias, void* __restrict__ Cv,
               int K, int N, int Mreal, int NBX){
  constexpr int BN = BM;
  constexpr int THREADS = WM*WN*64;
  static_assert(THREADS == BM*2, "stage mapping requires THREADS==2*BM");
  constexpr int PWM = BM/WM, PWN = BN/WN;
  constexpr int MF = PWM/16, NF = PWN/16, MFQ = MF/4;
  static_assert(MFQ*4 == MF, "");
  __shared__ char lds[2*2*BM*128];   // [db][A|B][BM rows][128B]

  int t = threadIdx.x, lane = t & 63, wave = t >> 6;
  int wr = wave / WN, wn = wave % WN;
  int l16 = lane & 15, g = lane >> 4;

  // bijective XCD-aware block swizzle
  int NB = gridDim.x;
  int q8 = NB >> 3, r8 = NB & 7;
  int xcd = blockIdx.x & 7, i8 = blockIdx.x >> 3;
  int swz = (xcd < r8 ? xcd*(q8+1) : r8*(q8+1) + (xcd-r8)*q8) + i8;
  int rb = (swz / NBX) * BM, cb = (swz % NBX) * BN;

  const int srow8 = t >> 3, sslot = t & 7;

  f32x4 acc[MF][NF];
  #pragma unroll
  for (int mf = 0; mf < MF; ++mf)
    #pragma unroll
    for (int nf = 0; nf < NF; ++nf)
      acc[mf][nf] = (f32x4){0.f,0.f,0.f,0.f};

#define STAGE(qq, kt, db) do{                                                  \
    int row_ = (qq)*(BM/4) + srow8;                                            \
    int kel_ = (sslot ^ (row_ & 7)) * 8;                                       \
    char* b_ = lds + (db)*(2*BM*128);                                          \
    gld_lds16(A  + (size_t)(rb+row_)*K + (kt)*64 + kel_,                       \
              (ushort*)(b_ + (qq)*(BM*32) + t*16));                            \
    gld_lds16(Bt + (size_t)(cb+row_)*K + (kt)*64 + kel_,                       \
              (ushort*)(b_ + BM*128 + (qq)*(BM*32) + t*16));                   \
  }while(0)

#define RDF(db, isB, row, kc)                                                  \
  (*(const bf16x8*)(lds + (db)*(2*BM*128) + (isB)*(BM*128) + (row)*128 +       \
                    ((((kc)*4 + g) ^ ((row) & 7)) << 4)))

  // prologue: stage tile 0 fully into buffer 0
  #pragma unroll
  for (int q = 0; q < 4; ++q) STAGE(q, 0, 0);

  int NT = K / 64;
  for (int tt = 0; tt < NT; ++tt){
    int db = tt & 1, dn = db ^ 1;
    bool pf = (tt + 1 < NT);
    if (pf){
      STAGE(0, tt+1, dn);
      asm volatile("s_waitcnt vmcnt(2)" ::: "memory");
    } else {
      asm volatile("s_waitcnt vmcnt(0)" ::: "memory");
    }
    __builtin_amdgcn_s_barrier();

    // B fragments for full K-tile (held across phases)
    bf16x8 bf[NF][2];
    #pragma unroll
    for (int nf = 0; nf < NF; ++nf)
      #pragma unroll
      for (int kc = 0; kc < 2; ++kc)
        bf[nf][kc] = RDF(db, 1, wn*PWN + nf*16 + l16, kc);

    // phase 0: quad 0
    {
      bf16x8 af[MFQ][2];
      #pragma unroll
      for (int mq = 0; mq < MFQ; ++mq)
        #pragma unroll
        for (int kc = 0; kc < 2; ++kc)
          af[mq][kc] = RDF(db, 0, wr*PWM + mq*16 + l16, kc);
      __builtin_amdgcn_s_setprio(1);
      #pragma unroll
      for (int mq = 0; mq < MFQ; ++mq)
        #pragma unroll
        for (int nf = 0; nf < NF; ++nf)
          #pragma unroll
          for (int kc = 0; kc < 2; ++kc)
            acc[mq][nf] = __builtin_amdgcn_mfma_f32_16x16x32_bf16(af[mq][kc], bf[nf][kc], acc[mq][nf], 0, 0, 0);
      __builtin_amdgcn_s_setprio(0);
    }
    __builtin_amdgcn_s_barrier();

    // phases 1..3: quads 1..3
    #pragma unroll
    for (int q = 1; q < 4; ++q){
      if (pf) STAGE(q, tt+1, dn);
      bf16x8 af[MFQ][2];
      #pragma unroll
      for (int mq = 0; mq < MFQ; ++mq)
        #pragma unroll
        for (int kc = 0; kc < 2; ++kc)
          af[mq][kc] = RDF(db, 0, wr*PWM + (q*MFQ + mq)*16 + l16, kc);
      __builtin_amdgcn_s_setprio(1);
      #pragma unroll
      for (int mq = 0; mq < MFQ; ++mq)
        #pragma unroll
        for (int nf = 0; nf < NF; ++nf)
          #pragma unroll
          for (int kc = 0; kc < 2; ++kc)
            acc[q*MFQ + mq][nf] = __builtin_amdgcn_mfma_f32_16x16x32_bf16(af[mq][kc], bf[nf][kc], acc[q*MFQ + mq][nf], 0, 0, 0);
      __builtin_amdgcn_s_setprio(0);
      __builtin_amdgcn_s_barrier();
    }
  }
#undef STAGE
#undef RDF

  // epilogue
  #pragma unroll
  for (int mf = 0; mf < MF; ++mf){
    #pragma unroll
    for (int nf = 0; nf < NF; ++nf){
      int col  = cb + wn*PWN + nf*16 + l16;
      int row0 = rb + wr*PWM + mf*16 + g*4;
      float bv = bias[col];
      #pragma unroll
      for (int j = 0; j < 4; ++j){
        int row = row0 + j;
        float val = acc[mf][nf][j] + bv;
        if (EPI == 1){
          ((ushort*)Cv)[(size_t)row*N + col] = f2bf(gelu_exact(val));
        } else {
          if (row < Mreal) ((float*)Cv)[(size_t)row*N + col] += val;
        }
      }
    }
  }
}

// ---------------- LayerNorm (fp32 in, bf16 out) ----------------
__global__ __launch_bounds__(256)
void ln_kernel(const float* __restrict__ x, const float* __restrict__ g,
               const float* __restrict__ b, ushort* __restrict__ y){
  int tok = blockIdx.x, t = threadIdx.x;
  const float* xp = x + (size_t)tok*HID;
  float v1 = xp[t], v2 = xp[t + 256];
  __shared__ float red[4];
  float s = v1 + v2;
  #pragma unroll
  for (int off = 32; off; off >>= 1) s += __shfl_xor(s, off);
  if ((t & 63) == 0) red[t >> 6] = s;
  __syncthreads();
  float mean = (red[0] + red[1] + red[2] + red[3]) * (1.0f/512.0f);
  __syncthreads();
  float d1 = v1 - mean, d2 = v2 - mean;
  s = d1*d1 + d2*d2;
  #pragma unroll
  for (int off = 32; off; off >>= 1) s += __shfl_xor(s, off);
  if ((t & 63) == 0) red[t >> 6] = s;
  __syncthreads();
  float var = (red[0] + red[1] + red[2] + red[3]) * (1.0f/512.0f);
  float rs  = rsqrtf(var + 1e-5f);
  ushort* yp = y + (size_t)tok*HID;
  yp[t]       = f2bf(d1*rs*g[t]       + b[t]);
  yp[t + 256] = f2bf(d2*rs*g[t + 256] + b[t + 256]);
}

// ---------------- MFMA QKV projection (per-head block-diagonal GEMM) -------
__global__ __launch_bounds__(256)
void qkv_mfma(const ushort* __restrict__ y,
              const ushort* __restrict__ wqb, const ushort* __restrict__ wkb,
              const ushort* __restrict__ wvb,
              const float* __restrict__ bq, const float* __restrict__ bk,
              const float* __restrict__ bv,
              ushort* __restrict__ q, ushort* __restrict__ k,
              ushort* __restrict__ vt){
  __shared__ short As[128*64];
  __shared__ short Bs[64*64];
  int t = threadIdx.x;
  int lane = t & 63, wave = t >> 6;
  int l16 = lane & 15, g = lane >> 4;
  int p  = blockIdx.y >> 3, hh = blockIdx.y & 7;
  int rb = blockIdx.x * 128;

  const ushort* W; const float* bias;
  if (p == 0)      { W = wqb; bias = bq; }
  else if (p == 1) { W = wkb; bias = bk; }
  else             { W = wvb; bias = bv; }
  W    += (size_t)hh * 64 * 64;
  bias += hh * 64;

  int srow = t >> 3, skoff = (t & 7) * 8;
  const ushort* Ab = y + (size_t)(rb + srow)*HID + hh*64 + skoff;
  const ushort* Bb = W + (size_t)srow*64 + skoff;
  #pragma unroll
  for (int i = 0; i < 4; ++i)
    gld_lds16(Ab + (size_t)(i*32)*HID, (ushort*)&As[t*8 + i*2048]);
  #pragma unroll
  for (int i = 0; i < 2; ++i)
    gld_lds16(Bb + (size_t)(i*32)*64, (ushort*)&Bs[t*8 + i*2048]);
  __syncthreads();

  f32x4 acc[2][4];
  #pragma unroll
  for (int m = 0; m < 2; ++m)
    #pragma unroll
    for (int n = 0; n < 4; ++n)
      acc[m][n] = (f32x4){0.f,0.f,0.f,0.f};

  #pragma unroll
  for (int kc = 0; kc < 2; ++kc){
    bf16x8 af[2], bfr[4];
    #pragma unroll
    for (int m = 0; m < 2; ++m)
      af[m] = *(bf16x8*)&As[(wave*32 + m*16 + l16)*64 + kc*32 + g*8];
    #pragma unroll
    for (int n = 0; n < 4; ++n)
      bfr[n] = *(bf16x8*)&Bs[(n*16 + l16)*64 + kc*32 + g*8];
    #pragma unroll
    for (int m = 0; m < 2; ++m)
      #pragma unroll
      for (int n = 0; n < 4; ++n)
        acc[m][n] = __builtin_amdgcn_mfma_f32_16x16x32_bf16(af[m], bfr[n], acc[m][n], 0, 0, 0);
  }

  #pragma unroll
  for (int m = 0; m < 2; ++m){
    #pragma unroll
    for (int nd = 0; nd < 4; ++nd){
      int e = nd*16 + l16;
      float bv2 = bias[e];
      #pragma unroll
      for (int j = 0; j < 4; ++j){
        int tok = rb + wave*32 + m*16 + g*4 + j;
        if (tok < TT){
          ushort r = f2bf(acc[m][nd][j] + bv2);
          if (p == 0)      q[(size_t)tok*HID + hh*64 + e] = r;
          else if (p == 1) k[(size_t)tok*HID + hh*64 + e] = r;
          else {
            int n = tok / SEQ, s = tok - n*SEQ;
            vt[((size_t)(n*NH + hh)*64 + e)*SPAD + s] = r;
          }
        }
      }
    }
  }
}

// ---------------- MFMA flash attention + residual add into h ----------------
__global__ __launch_bounds__(512, 4)
void attn_kernel(const ushort* __restrict__ q, const ushort* __restrict__ k,
                 const ushort* __restrict__ vt, float* __restrict__ h){
  __shared__ ushort Ks[SPAD*64];
  __shared__ ushort Vs[64*256];
  __shared__ ushort Ps[8][32*40];
  int nh = blockIdx.x;
  int n = nh >> 3, hd = nh & 7;
  int t = threadIdx.x;
  int lane = t & 63, wave = t >> 6;
  int l16 = lane & 15, g = lane >> 4;

  const ushort* kbase = k + ((size_t)n*SEQ)*HID + hd*64;
  for (int c = t; c < 224*8; c += 512){
    int s = c >> 3, c8 = (c & 7) * 8;
    int sr = s < SEQ ? s : SEQ-1;
    uint4 val = *(const uint4*)&kbase[(size_t)sr*HID + c8];
    int byte = s*128 + c8*2;
    byte ^= (s & 7) << 4;
    *(uint4*)((char*)Ks + byte) = val;
  }
  const ushort* vbase = vt + (size_t)nh*64*SPAD;
  for (int c = t; c < 64*32; c += 512){
    int d = c >> 5, kc = c & 31;
    uint4 val = {0u,0u,0u,0u};
    if (kc < 24){
      val = *(const uint4*)&vbase[(size_t)d*SPAD + kc*8];
    } else if (kc == 24){
      ushort tmp[8];
      #pragma unroll
      for (int e = 0; e < 8; ++e)
        tmp[e] = (192 + e < SEQ) ? vbase[(size_t)d*SPAD + 192 + e] : (ushort)0;
      val = *(uint4*)tmp;
    }
    int byte = d*512 + kc*16;
    byte ^= (d & 7) << 4;
    *(uint4*)((char*)Vs + byte) = val;
  }

  int qrow0 = wave * 32;
  bool wactive = qrow0 < SEQ;
  bf16x8 aq[2][2];
  if (wactive){
    #pragma unroll
    for (int m = 0; m < 2; ++m){
      int row = qrow0 + m*16 + l16;
      int sr = row < SEQ ? row : SEQ-1;
      const ushort* qp = q + ((size_t)n*SEQ + sr)*HID + hd*64;
      #pragma unroll
      for (int kc = 0; kc < 2; ++kc)
        aq[m][kc] = *(const bf16x8*)&qp[kc*32 + g*8];
    }
  }
  __syncthreads();

  if (wactive){
    ushort* myP = &Ps[wave][0];
    f32x4 accO[2][4];
    float mrun[2][4], lrun[2][4];
    #pragma unroll
    for (int m = 0; m < 2; ++m){
      #pragma unroll
      for (int nd = 0; nd < 4; ++nd) accO[m][nd] = (f32x4){0.f,0.f,0.f,0.f};
      #pragma unroll
      for (int j = 0; j < 4; ++j){ mrun[m][j] = -1e30f; lrun[m][j] = 0.f; }
    }

    for (int kt = 0; kt < 7; ++kt){
      f32x4 accS[2][2];
      #pragma unroll
      for (int m = 0; m < 2; ++m)
        #pragma unroll
        for (int nn = 0; nn < 2; ++nn) accS[m][nn] = (f32x4){0.f,0.f,0.f,0.f};
      #pragma unroll
      for (int kc = 0; kc < 2; ++kc){
        bf16x8 bk[2];
        #pragma unroll
        for (int nn = 0; nn < 2; ++nn){
          int srow = kt*32 + nn*16 + l16;
          int byte = srow*128 + kc*64 + g*16;
          byte ^= (srow & 7) << 4;
          bk[nn] = *(const bf16x8*)((const char*)Ks + byte);
        }
        #pragma unroll
        for (int m = 0; m < 2; ++m)
          #pragma unroll
          for (int nn = 0; nn < 2; ++nn)
            accS[m][nn] = __builtin_amdgcn_mfma_f32_16x16x32_bf16(aq[m][kc], bk[nn], accS[m][nn], 0, 0, 0);
      }
      bool kv0 = (kt*32 + l16) < SEQ;
      bool kv1 = (kt*32 + 16 + l16) < SEQ;
      #pragma unroll
      for (int m = 0; m < 2; ++m){
        #pragma unroll
        for (int j = 0; j < 4; ++j){
          float s0 = kv0 ? accS[m][0][j]*0.125f : -1e30f;
          float s1 = kv1 ? accS[m][1][j]*0.125f : -1e30f;
          float mx = fmaxf(s0, s1);
          mx = fmaxf(mx, __shfl_xor(mx, 1));
          mx = fmaxf(mx, __shfl_xor(mx, 2));
          mx = fmaxf(mx, __shfl_xor(mx, 4));
          mx = fmaxf(mx, __shfl_xor(mx, 8));
          float mold = mrun[m][j];
          float mnew = fmaxf(mold, mx);
          float corr = __expf(mold - mnew);
          mrun[m][j] = mnew;
          float p0 = __expf(s0 - mnew);
          float p1 = __expf(s1 - mnew);
          float rs = p0 + p1;
          rs += __shfl_xor(rs, 1);
          rs += __shfl_xor(rs, 2);
          rs += __shfl_xor(rs, 4);
          rs += __shfl_xor(rs, 8);
          lrun[m][j] = lrun[m][j]*corr + rs;
          #pragma unroll
          for (int nd = 0; nd < 4; ++nd) accO[m][nd][j] *= corr;
          int prow = m*16 + g*4 + j;
          myP[prow*40 + l16]      = f2bf(p0);
          myP[prow*40 + 16 + l16] = f2bf(p1);
        }
      }
      bf16x8 ap[2], bv[4];
      #pragma unroll
      for (int m = 0; m < 2; ++m)
        ap[m] = *(const bf16x8*)&myP[(m*16 + l16)*40 + g*8];
      #pragma unroll
      for (int nd = 0; nd < 4; ++nd){
        int d = nd*16 + l16;
        int byte = d*512 + kt*64 + g*16;
        byte ^= (d & 7) << 4;
        bv[nd] = *(const bf16x8*)((const char*)Vs + byte);
      }
      #pragma unroll
      for (int m = 0; m < 2; ++m)
        #pragma unroll
        for (int nd = 0; nd < 4; ++nd)
          accO[m][nd] = __builtin_amdgcn_mfma_f32_16x16x32_bf16(ap[m], bv[nd], accO[m][nd], 0, 0, 0);
    }

    #pragma unroll
    for (int m = 0; m < 2; ++m){
      #pragma unroll
      for (int j = 0; j < 4; ++j){
        int row = qrow0 + m*16 + g*4 + j;
        if (row < SEQ){
          float inv = 1.0f / lrun[m][j];
          float* hp = h + ((size_t)n*SEQ + row)*HID + hd*64;
          #pragma unroll
          for (int nd = 0; nd < 4; ++nd)
            hp[nd*16 + l16] += accO[m][nd][j] * inv;
        }
      }
    }
  }
}

// ---------------- head stage 1: logits ----------------
__global__ __launch_bounds__(256)
void head_logits(const float* __restrict__ h, const float* __restrict__ W,
                 const float* __restrict__ b, float* __restrict__ logits){
  int c0 = blockIdx.x * 8;
  __shared__ float Ws[512*8];
  int t = threadIdx.x;
  for (int i = t; i < 512*8; i += 256){
    int kx = i >> 3, c = i & 7;
    Ws[i] = W[(size_t)kx*OUTC + c0 + c];
  }
  __syncthreads();
  int n = t >> 2, g = t & 3;
  const float* hp = h + (size_t)n*SEQ*HID + g*128;
  float acc[8] = {};
  for (int kx = 0; kx < 128; ++kx){
    float hv = hp[kx];
    const float* wsr = &Ws[(g*128 + kx)*8];
    #pragma unroll
    for (int c = 0; c < 8; ++c) acc[c] += hv * wsr[c];
  }
  #pragma unroll
  for (int c = 0; c < 8; ++c){
    acc[c] += __shfl_xor(acc[c], 1);
    acc[c] += __shfl_xor(acc[c], 2);
  }
  if (g == 0){
    #pragma unroll
    for (int c = 0; c < 8; ++c)
      logits[(size_t)n*OUTC + c0 + c] = acc[c] + b[c0 + c];
  }
}

// ---------------- head stage 2: softmax ----------------
__global__ __launch_bounds__(256)
void head_softmax(const float* __restrict__ logits, float* __restrict__ out){
  int n = blockIdx.x, t = threadIdx.x;
  __shared__ float red[4];
  float v[4];
  #pragma unroll
  for (int j = 0; j < 4; ++j){
    int e = t + j*256;
    v[j] = (e < OUTC) ? logits[(size_t)n*OUTC + e] : -1e30f;
  }
  float mx = fmaxf(fmaxf(v[0], v[1]), fmaxf(v[2], v[3]));
  #pragma unroll
  for (int off = 32; off; off >>= 1) mx = fmaxf(mx, __shfl_xor(mx, off));
  if ((t & 63) == 0) red[t >> 6] = mx;
  __syncthreads();
  mx = fmaxf(fmaxf(red[0], red[1]), fmaxf(red[2], red[3]));
  __syncthreads();
  float sum = 0.f;
  #pragma unroll
  for (int j = 0; j < 4; ++j){ v[j] = __expf(v[j] - mx); sum += v[j]; }
  #pragma unroll
  for (int off = 32; off; off >>= 1) sum += __shfl_xor(sum, off);
  if ((t & 63) == 0) red[t >> 6] = sum;
  __syncthreads();
  sum = red[0] + red[1] + red[2] + red[3];
  float inv = 1.0f / sum;
  #pragma unroll
  for (int j = 0; j < 4; ++j){
    int e = t + j*256;
    if (e < OUTC) out[(size_t)n*OUTC + e] = v[j] * inv;
  }
}

extern "C" void kernel_launch(void* const* d_in, const int* in_sizes, int n_in,
                              void* d_out, int out_size, void* d_ws, size_t ws_size,
                              hipStream_t stream){
  const float* x       = (const float*)d_in[0];
  const float* embed_W = (const float*)d_in[1];
  const float* embed_b = (const float*)d_in[2];
  const float* cls     = (const float*)d_in[3];
  const float* ln1_g   = (const float*)d_in[4];
  const float* ln1_b   = (const float*)d_in[5];
  const float* qW      = (const float*)d_in[6];
  const float* qb      = (const float*)d_in[7];
  const float* kW      = (const float*)d_in[8];
  const float* kb      = (const float*)d_in[9];
  const float* vW      = (const float*)d_in[10];
  const float* vb      = (const float*)d_in[11];
  const float* ln2_g   = (const float*)d_in[12];
  const float* ln2_b   = (const float*)d_in[13];
  const float* mlp1_W  = (const float*)d_in[14];
  const float* mlp1_b  = (const float*)d_in[15];
  const float* mlp2_W  = (const float*)d_in[16];
  const float* mlp2_b  = (const float*)d_in[17];
  const float* head_W  = (const float*)d_in[18];
  const float* head_b  = (const float*)d_in[19];
  float* out = (float*)d_out;

  char* wsb = (char*)d_ws;
  float*  h   = (float*)wsb;                                   // M2*512 f32
  ushort* y   = (ushort*)(wsb + (size_t)M2*HID*4);             // M2*512 bf16
  float*  logits = (float*)y;                                  // reuse post-loop
  char*   un  = wsb + (size_t)M2*HID*4 + (size_t)M2*HID*2;     // union region
  ushort* qb_  = (ushort*)un;                                  // TT*512 bf16
  ushort* kb_  = qb_ + (size_t)TT*HID;
  ushort* vtb  = kb_ + (size_t)TT*HID;
  ushort* z1  = (ushort*)un;                                   // M2*2048 bf16
  ushort* p   = (ushort*)un;                                   // patches (pre-loop)
  char*   wts = un + (size_t)3*TT*HID*4;
  ushort* w1t = (ushort*)wts;
  ushort* w2t = w1t + (size_t)LAY*2048*512;
  ushort* wet = w2t + (size_t)LAY*2048*512;
  ushort* wqb = wet + (size_t)IN_DIM*HID;
  ushort* wkb = wqb + (size_t)LAY*NH*DH*DH;
  ushort* wvb = wkb + (size_t)LAY*NH*DH*DH;

  convt_kernel<<<dim3(2048/32, 512/32, LAY), 256, 0, stream>>>(mlp1_W, w1t, 512, 2048);
  convt_kernel<<<dim3(512/32, 2048/32, LAY), 256, 0, stream>>>(mlp2_W, w2t, 2048, 512);
  convt_kernel<<<dim3(512/32, 768/32, 1),    256, 0, stream>>>(embed_W, wet, 768, 512);
  {
    int cnt = LAY*NH*DH*DH;
    int grd = (cnt + 255)/256;
    cvt_kernel<<<grd, 256, 0, stream>>>(qW, wqb, cnt);
    cvt_kernel<<<grd, 256, 0, stream>>>(kW, wkb, cnt);
    cvt_kernel<<<grd, 256, 0, stream>>>(vW, wvb, cnt);
  }

  patchify_kernel<<<(NPTOK*IN_DIM)/256, 256, 0, stream>>>(x, p);
  cls_kernel<<<BATCH, 512, 0, stream>>>(cls, h);
  gemm_mfma<3><<<dim3(HID/128, NPTOK/128), 256, 0, stream>>>(
      p, wet, embed_b, h, IN_DIM, HID, NPTOK);

  for (int l = 0; l < LAY; ++l){
    ln_kernel<<<TT, 256, 0, stream>>>(h, ln1_g + l*HID, ln1_b + l*HID, y);
    qkv_mfma<<<dim3(M2/128, 24), 256, 0, stream>>>(
        y,
        wqb + (size_t)l*NH*DH*DH, wkb + (size_t)l*NH*DH*DH, wvb + (size_t)l*NH*DH*DH,
        qb + (size_t)l*HID, kb + (size_t)l*HID, vb + (size_t)l*HID,
        qb_, kb_, vtb);
    attn_kernel<<<BATCH*NH, 512, 0, stream>>>(qb_, kb_, vtb, h);
    ln_kernel<<<TT, 256, 0, stream>>>(h, ln2_g + l*HID, ln2_b + l*HID, y);
    // MLP1: [M2,512] @ [2048,512]^T -> z1 (gelu, bf16). 256^2 tile, 8 waves.
    gemm_pipe<256, 2, 4, 1><<<(2048/256)*(M2/256), 512, 0, stream>>>(
        y, w1t + (size_t)l*2048*512, mlp1_b + (size_t)l*4*HID, z1,
        HID, 4*HID, TT, 2048/256);
    // MLP2: [M2,2048] @ [512,2048]^T -> h += (fp32). 128^2 tile, 4 waves.
    gemm_pipe<128, 2, 2, 2><<<(512/128)*(M2/128), 256, 0, stream>>>(
        z1, w2t + (size_t)l*2048*512, mlp2_b + (size_t)l*HID, h,
        4*HID, HID, TT, 512/128);
  }

  head_logits<<<125, 256, 0, stream>>>(h, head_W, head_b, logits);
  head_softmax<<<BATCH, 256, 0, stream>>>(logits, out);
}